// Round 7
// baseline (165.697 us; speedup 1.0000x reference)
//
#include <hip/hip_runtime.h>

// Causal MHA: B=2, H=16, S=2048, DH=64. fp32 in/out. bf16 MFMA inside.
// R16: PERSISTENT blocks + dynamic LPT work-stealing on the proven R12/R15
// core. Theory ledger: LDS traffic (R13), barriers (R14), item granularity
// (R15) all falsified -- the invariant across all is ~35% occupancy (~11
// waves/CU) regardless of LDS capacity or item shape => sustained residency
// (block churn/dispatch ramp over 2016 short blocks) is the limiter; at
// ~2.8 waves/SIMD the per-tile dep chain can't be hidden. Fix: launch
// exactly 1280 blocks (5/CU, LDS-capacity) that LOOP over work items via a
// global atomic counter (items LPT-ordered longest-first => greedy near-
// optimal makespan). Occupancy pinned at 5 blocks/CU, zero churn, scheduler-
// independent balance. 2016 atomics total (no fences, no spinning). ctr in
// ws, zeroed by prep each captured iteration => graph-replay safe. Top-of-
// loop barrier doubles as pst/qs reuse fence. Core kept verbatim from R15:
// 256thr/4-wave prow scheme, LDS K/V staging + reg prefetch, 2 barriers/
// tile, in-LDS Pt, l via ones-MFMA, fast_exp2, -M2 C-init, v_perm pack,
// LDP=72, setprio around MFMA, RTAB (63 items/bh, len<=11), combine 2-3
// partials, prep (bf16 Q*0.125*log2e, K, V^T dword-swizzled), analytic
// causal mask. Fallbacks unchanged.

#define S_LEN  2048
#define DHDIM  64
#define NHEADS 32   // B*H
#define LDP    72   // padded LDS row length in shorts (144B = 9*16B)
#define M2     23.083120654223414f   // 16 * log2(e)
#define QSCALE 0.18033688011117658f  // 0.125 * log2(e)
#define NSLOT  52   // partial slots per bh
#define NITEMS 2016 // 63 ranks x 32 bh

typedef __attribute__((ext_vector_type(8))) short bf16x8;
typedef __attribute__((ext_vector_type(4))) float f32x4;

// rank table: 63 items per bh, LPT (desc length) order.
// entry = qt<<24 | k0<<16 | k1<<8 | slot  (slot 255 = whole row, direct O)
#define RT(qt,k0,k1,sl) ((unsigned)(qt)<<24 | (unsigned)(k0)<<16 | (unsigned)(k1)<<8 | (unsigned)(sl))
__device__ __constant__ unsigned RTAB[63] = {
    RT(31,0,11,49),  RT(31,11,22,50), RT(30,0,11,46),  RT(21,0,11,20),
    RT(21,11,22,21), RT(20,0,11,18),  RT(10,0,11,255),
    RT(31,22,32,51), RT(30,11,21,47), RT(30,21,31,48), RT(29,0,10,43),
    RT(29,10,20,44), RT(29,20,30,45), RT(28,0,10,40),  RT(28,10,20,41),
    RT(27,0,10,37),  RT(20,11,21,19), RT(19,0,10,16),  RT(19,10,20,17),
    RT(18,0,10,14),  RT(9,0,10,255),
    RT(28,20,29,42), RT(27,10,19,38), RT(27,19,28,39), RT(26,0,9,34),
    RT(26,9,18,35),  RT(26,18,27,36), RT(25,0,9,31),   RT(25,9,18,32),
    RT(24,0,9,28),   RT(18,10,19,15), RT(17,0,9,12),   RT(17,9,18,13),
    RT(16,0,9,10),   RT(8,0,9,255),
    RT(25,18,26,33), RT(24,9,17,29),  RT(24,17,25,30), RT(23,0,8,25),
    RT(23,8,16,26),  RT(23,16,24,27), RT(22,0,8,22),   RT(22,8,16,23),
    RT(16,9,17,11),  RT(15,0,8,8),    RT(15,8,16,9),   RT(14,0,8,6),
    RT(7,0,8,255),
    RT(22,16,23,24), RT(14,8,15,7),   RT(13,0,7,4),    RT(13,7,14,5),
    RT(12,0,7,2),    RT(6,0,7,255),
    RT(12,7,13,3),   RT(11,0,6,0),    RT(11,6,12,1),   RT(5,0,6,255),
    RT(4,0,5,255),   RT(3,0,4,255),   RT(2,0,3,255),   RT(1,0,2,255),
    RT(0,0,1,255)};

__device__ __forceinline__ float fast_exp2(float x) {
#if __has_builtin(__builtin_amdgcn_exp2f)
    return __builtin_amdgcn_exp2f(x);
#else
    return exp2f(x);
#endif
}
__device__ __forceinline__ unsigned short f2bf(float f) { // RNE
    unsigned u = __float_as_uint(f);
    return (unsigned short)((u + 0x7fffu + ((u >> 16) & 1u)) >> 16);
}
__device__ __forceinline__ void ld8(const float* p, float* f) {
    float4 a = *(const float4*)p, b = *(const float4*)(p + 4);
    f[0]=a.x; f[1]=a.y; f[2]=a.z; f[3]=a.w; f[4]=b.x; f[5]=b.y; f[6]=b.z; f[7]=b.w;
}
__device__ __forceinline__ uint4 pack8(const float* f, float scale) {
    union { uint4 v; unsigned short s[8]; } w;
    #pragma unroll
    for (int j = 0; j < 8; j++) w.s[j] = f2bf(f[j] * scale);
    return w.v;
}
// combine high-16s of two floats into one dword: [lo16=a.hi16, hi16=b.hi16]
__device__ __forceinline__ unsigned packhi(float a, float b) {
#if __has_builtin(__builtin_amdgcn_perm)
    return __builtin_amdgcn_perm(__float_as_uint(b), __float_as_uint(a), 0x07060302u);
#else
    return (__float_as_uint(a) >> 16) | (__float_as_uint(b) & 0xffff0000u);
#endif
}

// ---- pre-pass: per block (st, bh): V 64x64 tile -> bf16 V^T tile, plus a
// 4096-elem chunk of Q (scaled) and K -> bf16. Block (0,0) zeroes ctr.
__global__ __launch_bounds__(256) void prep(
    const float* __restrict__ Qf, const float* __restrict__ Kf,
    const float* __restrict__ Vf, unsigned short* __restrict__ qb,
    unsigned short* __restrict__ kb, unsigned short* __restrict__ vtb,
    int* __restrict__ ctr)
{
    const int st = blockIdx.x, bh = blockIdx.y;
    if (ctr && st == 0 && bh == 0 && threadIdx.x == 0) *ctr = 0;
    __shared__ unsigned lt32[64][LDP / 2];   // dword view: 36 dwords/row
    const float* vp = Vf + ((size_t)bh * S_LEN + st * 64) * DHDIM;
    {
        const int c = threadIdx.x;
        const int sp = c >> 3;            // s-pair index 0..31
        const int d0 = (c & 7) * 8;
        float fa[8], fb[8];
        ld8(vp + (2 * sp) * DHDIM + d0, fa);
        ld8(vp + (2 * sp + 1) * DHDIM + d0, fb);
        #pragma unroll
        for (int j = 0; j < 8; j++) {
            int d = d0 + j;
            int colw = (sp & 3) | ((((sp >> 2) ^ (d >> 3)) & 7) << 2);
            lt32[d][colw] = (unsigned)f2bf(fa[j]) | ((unsigned)f2bf(fb[j]) << 16);
        }
    }
    size_t off = ((size_t)(bh * 32 + st) * 4096) + (size_t)threadIdx.x * 16;
    float f[8];
    ld8(Qf + off, f);     *(uint4*)(qb + off)     = pack8(f, QSCALE);
    ld8(Qf + off + 8, f); *(uint4*)(qb + off + 8) = pack8(f, QSCALE);
    ld8(Kf + off, f);     *(uint4*)(kb + off)     = pack8(f, 1.0f);
    ld8(Kf + off + 8, f); *(uint4*)(kb + off + 8) = pack8(f, 1.0f);
    __syncthreads();
    unsigned short* op = vtb + (size_t)bh * DHDIM * S_LEN + st * 64;
    for (int c = threadIdx.x; c < 512; c += 256) {
        int d = c >> 3, q = c & 7;
        int colw = ((q ^ (d >> 3)) & 7) << 2;
        *(uint4*)(op + (size_t)d * S_LEN + q * 8) = *(const uint4*)&lt32[d][colw];
    }
}

// ---- main: 1280 PERSISTENT blocks; dynamic work-stealing over NITEMS items.
// R12 core per item: 256 threads, 4 waves, prow scheme, LDS staging + prefetch.
__global__ __launch_bounds__(256) void fattn_splitk(
    const unsigned short* __restrict__ Qp, const unsigned short* __restrict__ Kp,
    const unsigned short* __restrict__ Vp,
    float* __restrict__ pO, float* __restrict__ pL, float* __restrict__ O,
    int* __restrict__ ctr)
{
    __shared__ unsigned short smem[192 * LDP]; // 27.6 KB -> 5 blocks/CU
    __shared__ int s_idx;
    unsigned short (*ks)[LDP]  = (unsigned short(*)[LDP])smem;
    unsigned short (*vts)[LDP] = (unsigned short(*)[LDP])(smem + 64 * LDP);
    unsigned short (*qs)[LDP]  = (unsigned short(*)[LDP])(smem + 128 * LDP);
    unsigned short (*pst)[LDP] = qs; // overlay: wave w touches only rows w*16..+15

    const int tid = threadIdx.x;
    const int wave = tid >> 6, lane = tid & 63;
    const int quad = lane >> 4, l16 = lane & 15;
    const int prow = wave * 16 + l16; // this lane's q-row (transposed scheme)
    const int sr = tid >> 3, sc = (tid & 7) * 8;   // staging rows sr, sr+32

    bf16x8 ones;
    #pragma unroll
    for (int j = 0; j < 8; j++) ones[j] = (short)0x3F80; // bf16 1.0

    for (;;) {
        if (tid == 0) s_idx = atomicAdd(ctr, 1);
        __syncthreads();   // publishes s_idx; also fences prev item's LDS reads
        const int idx = s_idx;
        if (idx >= NITEMS) break;

        const unsigned e = RTAB[idx >> 5];   // LPT order: longest items first
        const int bh = idx & 31;
        const int qt = e >> 24;
        const int k0 = (e >> 16) & 255;
        const int k1 = (e >> 8) & 255;
        const int sl = e & 255;
        const bool whole = (sl == 255);

        // ---- stage Q tile (bf16, pre-scaled by prep)
        {
            const unsigned short* src = Qp + ((size_t)bh * S_LEN + qt * 64) * DHDIM;
            for (int c = tid; c < 512; c += 256) {
                int row = c >> 3, c8 = (c & 7) * 8;
                *(uint4*)&qs[row][c8] = *(const uint4*)(src + row * DHDIM + c8);
            }
        }
        __syncthreads();

        const bf16x8 bq0 = *(const bf16x8*)&qs[prow][quad * 8];
        const bf16x8 bq1 = *(const bf16x8*)&qs[prow][32 + quad * 8];

        f32x4 of[4];
        f32x4 of_l = (f32x4){0.f, 0.f, 0.f, 0.f}; // ones-row * Pt = l per q-col
        #pragma unroll
        for (int n = 0; n < 4; n++) of[n] = (f32x4){0.f, 0.f, 0.f, 0.f};

        // ---- T14 prefetch: staging registers for the next K/V tile
        const unsigned short* Kbh = Kp + (size_t)bh * S_LEN * DHDIM;
        const unsigned short* Vbh = Vp + (size_t)bh * DHDIM * S_LEN;
        uint4 kr0, kr1, vr0, vr1;
        {
            const unsigned short* ksrc = Kbh + (size_t)k0 * 64 * DHDIM;
            const unsigned short* vsrc = Vbh + k0 * 64;
            kr0 = *(const uint4*)(ksrc + sr * DHDIM + sc);
            kr1 = *(const uint4*)(ksrc + (sr + 32) * DHDIM + sc);
            vr0 = *(const uint4*)(vsrc + (size_t)sr * S_LEN + sc);
            vr1 = *(const uint4*)(vsrc + (size_t)(sr + 32) * S_LEN + sc);
        }

        for (int kt = k0; kt < k1; kt++) {
            __syncthreads(); // prior iter done with ks/vts

            // write current prefetched tile to LDS (vmcnt wait folds in here)
            *(uint4*)&ks[sr][sc]       = kr0;
            *(uint4*)&ks[sr + 32][sc]  = kr1;
            *(uint4*)&vts[sr][sc]      = vr0;
            *(uint4*)&vts[sr + 32][sc] = vr1;

            // issue next tile's global loads; latency hides under compute below
            if (kt + 1 < k1) {
                const unsigned short* ksrc = Kbh + (size_t)(kt + 1) * 64 * DHDIM;
                const unsigned short* vsrc = Vbh + (kt + 1) * 64;
                kr0 = *(const uint4*)(ksrc + sr * DHDIM + sc);
                kr1 = *(const uint4*)(ksrc + (sr + 32) * DHDIM + sc);
                vr0 = *(const uint4*)(vsrc + (size_t)sr * S_LEN + sc);
                vr1 = *(const uint4*)(vsrc + (size_t)(sr + 32) * S_LEN + sc);
            }
            __syncthreads();

            // ---- St tile n; C-init = -M2 folds the softmax subtract
            __builtin_amdgcn_s_setprio(1);
            f32x4 sf[4];
            #pragma unroll
            for (int n = 0; n < 4; n++) {
                bf16x8 ak0 = *(const bf16x8*)&ks[n * 16 + l16][quad * 8];
                bf16x8 ak1 = *(const bf16x8*)&ks[n * 16 + l16][32 + quad * 8];
                sf[n] = (f32x4){-M2, -M2, -M2, -M2};
                sf[n] = __builtin_amdgcn_mfma_f32_16x16x32_bf16(ak0, bq0, sf[n], 0, 0, 0);
                sf[n] = __builtin_amdgcn_mfma_f32_16x16x32_bf16(ak1, bq1, sf[n], 0, 0, 0);
            }
            __builtin_amdgcn_s_setprio(0);

            // ---- p = exp2(sf), causal zero (diag tile), pack Pt
            const bool diag = (kt == qt);
            #pragma unroll
            for (int n = 0; n < 4; n++) {
                float p[4];
                #pragma unroll
                for (int r = 0; r < 4; r++) {
                    p[r] = fast_exp2(sf[n][r]);
                    if (diag && (n * 16 + quad * 4 + r > prow)) p[r] = 0.f;
                }
                uint2 dw;
                dw.x = packhi(p[0], p[1]); // bf16 truncation via byte-select
                dw.y = packhi(p[2], p[3]);
                *(uint2*)&pst[prow][n * 16 + quad * 4] = dw;
            }
            asm volatile("s_waitcnt lgkmcnt(0)" ::: "memory"); // wave-local Pt fence

            __builtin_amdgcn_s_setprio(1);
            bf16x8 bp0 = *(const bf16x8*)&pst[prow][quad * 8];
            bf16x8 bp1 = *(const bf16x8*)&pst[prow][32 + quad * 8];
            of_l = __builtin_amdgcn_mfma_f32_16x16x32_bf16(ones, bp0, of_l, 0, 0, 0);
            of_l = __builtin_amdgcn_mfma_f32_16x16x32_bf16(ones, bp1, of_l, 0, 0, 0);
            #pragma unroll
            for (int n = 0; n < 4; n++) {
                bf16x8 av0 = *(const bf16x8*)&vts[n * 16 + l16][quad * 8];
                bf16x8 av1 = *(const bf16x8*)&vts[n * 16 + l16][32 + quad * 8];
                of[n] = __builtin_amdgcn_mfma_f32_16x16x32_bf16(av0, bp0, of[n], 0, 0, 0);
                of[n] = __builtin_amdgcn_mfma_f32_16x16x32_bf16(av1, bp1, of[n], 0, 0, 0);
            }
            __builtin_amdgcn_s_setprio(0);
        }

        if (whole) {
            // short row: normalize and write O directly, no partial traffic
            const float inv = 1.f / of_l[0];
            float* op = O + ((size_t)bh * S_LEN + qt * 64 + prow) * DHDIM;
            #pragma unroll
            for (int n = 0; n < 4; n++)
                *(float4*)(op + n * 16 + quad * 4) = make_float4(
                    of[n][0] * inv, of[n][1] * inv, of[n][2] * inv, of[n][3] * inv);
        } else {
            // piece: write unnormalized partial + per-row l (fixed-max softmax
            // => partials combine exactly by summation in the combine kernel)
            const int slot = bh * NSLOT + sl;
            if (quad == 0) pL[slot * 64 + prow] = of_l[0];
            float* op = pO + (size_t)slot * 4096 + prow * 64;
            #pragma unroll
            for (int n = 0; n < 4; n++)
                *(float4*)(op + n * 16 + quad * 4) =
                    make_float4(of[n][0], of[n][1], of[n][2], of[n][3]);
        }
    }
}

// ---- combine: O = sum(Oi) / sum(li), per (bh, qt) for qt in [11,31]
__global__ __launch_bounds__(256) void combine(
    const float* __restrict__ pO, const float* __restrict__ pL,
    float* __restrict__ O)
{
    const int qt = 11 + blockIdx.x, bh = blockIdx.y;
    int base, cnt;
    if (qt < 22) { base = (qt - 11) * 2;      cnt = 2; }
    else         { base = 22 + 3 * (qt - 22); cnt = 3; }
    const int sb = bh * NSLOT + base;
    const float* A = pO + (size_t)sb * 4096;
    float* out = O + ((size_t)bh * S_LEN + qt * 64) * DHDIM;
    #pragma unroll
    for (int k = 0; k < 4; k++) {
        int c = threadIdx.x + k * 256;     // float4 chunk 0..1023
        int row = c >> 4;
        float l = pL[sb * 64 + row] + pL[(sb + 1) * 64 + row];
        float4 a = *(const float4*)(A + c * 4);
        float4 b = *(const float4*)(A + 4096 + c * 4);
        float4 s = make_float4(a.x + b.x, a.y + b.y, a.z + b.z, a.w + b.w);
        if (cnt == 3) {
            l += pL[(sb + 2) * 64 + row];
            float4 d = *(const float4*)(A + 8192 + c * 4);
            s = make_float4(s.x + d.x, s.y + d.y, s.z + d.z, s.w + d.w);
        }
        float inv = 1.f / l;
        *(float4*)(out + c * 4) = make_float4(
            s.x * inv, s.y * inv, s.z * inv, s.w * inv);
    }
}

// ---- fallback kernels (whole-row blocks), used when ws too small
template <bool PRE>
__global__ __launch_bounds__(256) void fattn_kernel(
    const void* __restrict__ Qp, const void* __restrict__ Kp,
    const void* __restrict__ Vp, float* __restrict__ O)
{
    __shared__ unsigned short smem[192 * LDP];
    unsigned short (*ks)[LDP]  = (unsigned short(*)[LDP])smem;
    unsigned short (*vts)[LDP] = (unsigned short(*)[LDP])(smem + 64 * LDP);
    unsigned short (*qs)[LDP]  = (unsigned short(*)[LDP])(smem + 128 * LDP);
    unsigned short (*pst)[LDP] = qs;

    const int id = blockIdx.y * 32 + blockIdx.x;
    const int g  = id >> 8;
    const int r8 = id & 255;
    const int bh = r8 >> 3;
    const int s8 = r8 & 7;
    const int qt = (g == 0) ? 31 - 2 * s8 : (g == 1) ? 2 * s8
                 : (g == 2) ? 30 - 2 * s8 : 2 * s8 + 1;

    const int tid = threadIdx.x;
    const int wave = tid >> 6, lane = tid & 63;
    const int quad = lane >> 4, l16 = lane & 15;

    if constexpr (PRE) {
        const unsigned short* src = (const unsigned short*)Qp
            + ((size_t)bh * S_LEN + qt * 64) * DHDIM;
        for (int c = tid; c < 512; c += 256) {
            int row = c >> 3, c8 = (c & 7) * 8;
            *(uint4*)&qs[row][c8] = *(const uint4*)(src + row * DHDIM + c8);
        }
    } else {
        const float* src = (const float*)Qp + ((size_t)bh * S_LEN + qt * 64) * DHDIM;
        for (int c = tid; c < 512; c += 256) {
            int row = c >> 3, c8 = (c & 7) * 8;
            float f[8]; ld8(src + row * DHDIM + c8, f);
            *(uint4*)&qs[row][c8] = pack8(f, QSCALE);
        }
    }
    __syncthreads();

    const int prow = wave * 16 + l16;
    const bf16x8 bq0 = *(const bf16x8*)&qs[prow][quad * 8];
    const bf16x8 bq1 = *(const bf16x8*)&qs[prow][32 + quad * 8];

    float l_p = 0.f;
    f32x4 of[4];
    #pragma unroll
    for (int n = 0; n < 4; n++) of[n] = (f32x4){0.f, 0.f, 0.f, 0.f};

    for (int kt = 0; kt <= qt; kt++) {
        __syncthreads();
        if constexpr (PRE) {
            const unsigned short* ksrc = (const unsigned short*)Kp
                + ((size_t)bh * S_LEN + kt * 64) * DHDIM;
            const unsigned short* vsrc = (const unsigned short*)Vp
                + (size_t)bh * DHDIM * S_LEN + kt * 64;
            for (int c = tid; c < 512; c += 256) {
                int row = c >> 3, c8 = (c & 7) * 8;
                *(uint4*)&ks[row][c8]  = *(const uint4*)(ksrc + row * DHDIM + c8);
                *(uint4*)&vts[row][c8] = *(const uint4*)(vsrc + (size_t)row * S_LEN + c8);
            }
        } else {
            const float* ksrc = (const float*)Kp + ((size_t)bh * S_LEN + kt * 64) * DHDIM;
            const float* vsrc = (const float*)Vp + ((size_t)bh * S_LEN + kt * 64) * DHDIM;
            for (int c = tid; c < 512; c += 256) {
                int row = c >> 3, c8 = (c & 7) * 8;
                float f[8];
                ld8(ksrc + row * DHDIM + c8, f);
                *(uint4*)&ks[row][c8] = pack8(f, 1.0f);
                ld8(vsrc + row * DHDIM + c8, f);
                #pragma unroll
                for (int j = 0; j < 8; j++) vts[c8 + j][row] = f2bf(f[j]);
            }
        }
        __syncthreads();

        f32x4 sf[4];
        #pragma unroll
        for (int n = 0; n < 4; n++) {
            bf16x8 ak0 = *(const bf16x8*)&ks[n * 16 + l16][quad * 8];
            bf16x8 ak1 = *(const bf16x8*)&ks[n * 16 + l16][32 + quad * 8];
            sf[n] = (f32x4){-M2, -M2, -M2, -M2};
            sf[n] = __builtin_amdgcn_mfma_f32_16x16x32_bf16(ak0, bq0, sf[n], 0, 0, 0);
            sf[n] = __builtin_amdgcn_mfma_f32_16x16x32_bf16(ak1, bq1, sf[n], 0, 0, 0);
        }

        const bool diag = (kt == qt);
        #pragma unroll
        for (int n = 0; n < 4; n++) {
            float p[4];
            #pragma unroll
            for (int r = 0; r < 4; r++) {
                p[r] = fast_exp2(sf[n][r]);
                if (diag && (n * 16 + quad * 4 + r > prow)) p[r] = 0.f;
                l_p += p[r];
            }
            uint2 dw;
            dw.x = packhi(p[0], p[1]);
            dw.y = packhi(p[2], p[3]);
            *(uint2*)&pst[prow][n * 16 + quad * 4] = dw;
        }
        asm volatile("s_waitcnt lgkmcnt(0)" ::: "memory");

        bf16x8 bp0 = *(const bf16x8*)&pst[prow][quad * 8];
        bf16x8 bp1 = *(const bf16x8*)&pst[prow][32 + quad * 8];
        #pragma unroll
        for (int n = 0; n < 4; n++) {
            bf16x8 av0 = *(const bf16x8*)&vts[n * 16 + l16][quad * 8];
            bf16x8 av1 = *(const bf16x8*)&vts[n * 16 + l16][32 + quad * 8];
            of[n] = __builtin_amdgcn_mfma_f32_16x16x32_bf16(av0, bp0, of[n], 0, 0, 0);
            of[n] = __builtin_amdgcn_mfma_f32_16x16x32_bf16(av1, bp1, of[n], 0, 0, 0);
        }
    }

    l_p += __shfl_xor(l_p, 16);
    l_p += __shfl_xor(l_p, 32);
    const float inv = 1.f / l_p;
    float* op = O + ((size_t)bh * S_LEN + qt * 64 + prow) * DHDIM;
    #pragma unroll
    for (int n = 0; n < 4; n++)
        *(float4*)(op + n * 16 + quad * 4) = make_float4(
            of[n][0] * inv, of[n][1] * inv, of[n][2] * inv, of[n][3] * inv);
}

extern "C" void kernel_launch(void* const* d_in, const int* in_sizes, int n_in,
                              void* d_out, int out_size, void* d_ws, size_t ws_size,
                              hipStream_t stream) {
    const float* Q = (const float*)d_in[0];
    const float* K = (const float*)d_in[1];
    const float* V = (const float*)d_in[2];
    // d_in[3] = causal mask: analytic, not read.
    float* O = (float*)d_out;
    const size_t N = (size_t)NHEADS * S_LEN * DHDIM;      // 4,194,304 elems
    const size_t prepB  = 3 * N * sizeof(unsigned short); // 25.2 MB
    // 52 partial slots per bh (qt>=11 pieces): O-partials + l
    const size_t partB  = (size_t)NSLOT * 32 * (4096 + 64) * sizeof(float); // 27.7 MB
    const size_t ctrB   = 64;                             // work-steal counter

    if (d_ws && ws_size >= prepB + partB + ctrB) {
        unsigned short* qb  = (unsigned short*)d_ws;
        unsigned short* kb  = qb + N;
        unsigned short* vtb = kb + N;
        float* pO = (float*)((char*)d_ws + prepB);
        float* pL = pO + (size_t)NSLOT * 32 * 4096;
        int* ctr  = (int*)((char*)d_ws + prepB + partB);
        prep<<<dim3(S_LEN / 64, NHEADS), 256, 0, stream>>>(Q, K, V, qb, kb, vtb, ctr);
        fattn_splitk<<<dim3(1280), 256, 0, stream>>>(qb, kb, vtb, pO, pL, O, ctr);
        combine<<<dim3(21, 32), 256, 0, stream>>>(pO, pL, O);
    } else if (d_ws && ws_size >= prepB) {
        unsigned short* qb  = (unsigned short*)d_ws;
        unsigned short* kb  = qb + N;
        unsigned short* vtb = kb + N;
        prep<<<dim3(S_LEN / 64, NHEADS), 256, 0, stream>>>(Q, K, V, qb, kb, vtb, nullptr);
        fattn_kernel<true><<<dim3(32, 32), 256, 0, stream>>>(qb, kb, vtb, O);
    } else {
        fattn_kernel<false><<<dim3(32, 32), 256, 0, stream>>>(Q, K, V, O);
    }
}

// Round 8
// 144.703 us; speedup vs baseline: 1.1451x; 1.1451x over previous
//
#include <hip/hip_runtime.h>

// Causal MHA: B=2, H=16, S=2048, DH=64. fp32 in/out. bf16 MFMA inside.
// R17: 2-TILE WINDOWS (wave-level ILP) on the proven R15 core.
// R16 post-mortem: work-stealing scrambled bh across blocks -> FETCH 13->98MB
// (L2 locality destroyed), and persistent blocks did NOT raise occupancy ->
// residency/churn theories dead. Surviving suspect: the serial per-tile chain
// (ds_read->MFMA->exp2->pack->fence->MFMA) at ~2.8 waves/SIMD has no cross-
// wave overlap. Fix = ILP within the wave: unroll kt by 2, stage BOTH tiles
// in one barrier window (ksA/ksB/vtsA/vtsB, 46KB LDS -> 3 blocks/CU = 12-wave
// cap ~= measured 11). Per window: bar; write A+B; prefetch next pair; bar;
// St_A+St_B (16 independent MFMA -- B's St fills A's softmax/fence stalls);
// softmax A -> pst -> fence -> PV_A; softmax B -> pst (wave-local reuse, no
// barrier) -> fence -> PV_B. Barriers per tile HALVED. Static grid/RTAB/
// combine/prep reverted to R15 verbatim (restores FETCH ~13MB).
// Kept: RTAB items len<=11 (R15), reg prefetch (R12), l via ones-MFMA,
// fast_exp2, fixed-max softmax (partials combine exactly), -M2 C-init,
// v_perm pack, LDP=72, setprio, prep (bf16 Q*0.125*log2e, K, V^T), analytic
// causal mask. Fallbacks unchanged.

#define S_LEN  2048
#define DHDIM  64
#define NHEADS 32   // B*H
#define LDP    72   // padded LDS row length in shorts (144B = 9*16B)
#define M2     23.083120654223414f   // 16 * log2(e)
#define QSCALE 0.18033688011117658f  // 0.125 * log2(e)
#define NSLOT  52   // partial slots per bh

typedef __attribute__((ext_vector_type(8))) short bf16x8;
typedef __attribute__((ext_vector_type(4))) float f32x4;

// rank table: 63 items per bh, LPT (desc length) order.
// entry = qt<<24 | k0<<16 | k1<<8 | slot  (slot 255 = whole row, direct O)
#define RT(qt,k0,k1,sl) ((unsigned)(qt)<<24 | (unsigned)(k0)<<16 | (unsigned)(k1)<<8 | (unsigned)(sl))
__device__ __constant__ unsigned RTAB[63] = {
    RT(31,0,11,49),  RT(31,11,22,50), RT(30,0,11,46),  RT(21,0,11,20),
    RT(21,11,22,21), RT(20,0,11,18),  RT(10,0,11,255),
    RT(31,22,32,51), RT(30,11,21,47), RT(30,21,31,48), RT(29,0,10,43),
    RT(29,10,20,44), RT(29,20,30,45), RT(28,0,10,40),  RT(28,10,20,41),
    RT(27,0,10,37),  RT(20,11,21,19), RT(19,0,10,16),  RT(19,10,20,17),
    RT(18,0,10,14),  RT(9,0,10,255),
    RT(28,20,29,42), RT(27,10,19,38), RT(27,19,28,39), RT(26,0,9,34),
    RT(26,9,18,35),  RT(26,18,27,36), RT(25,0,9,31),   RT(25,9,18,32),
    RT(24,0,9,28),   RT(18,10,19,15), RT(17,0,9,12),   RT(17,9,18,13),
    RT(16,0,9,10),   RT(8,0,9,255),
    RT(25,18,26,33), RT(24,9,17,29),  RT(24,17,25,30), RT(23,0,8,25),
    RT(23,8,16,26),  RT(23,16,24,27), RT(22,0,8,22),   RT(22,8,16,23),
    RT(16,9,17,11),  RT(15,0,8,8),    RT(15,8,16,9),   RT(14,0,8,6),
    RT(7,0,8,255),
    RT(22,16,23,24), RT(14,8,15,7),   RT(13,0,7,4),    RT(13,7,14,5),
    RT(12,0,7,2),    RT(6,0,7,255),
    RT(12,7,13,3),   RT(11,0,6,0),    RT(11,6,12,1),   RT(5,0,6,255),
    RT(4,0,5,255),   RT(3,0,4,255),   RT(2,0,3,255),   RT(1,0,2,255),
    RT(0,0,1,255)};

__device__ __forceinline__ float fast_exp2(float x) {
#if __has_builtin(__builtin_amdgcn_exp2f)
    return __builtin_amdgcn_exp2f(x);
#else
    return exp2f(x);
#endif
}
__device__ __forceinline__ unsigned short f2bf(float f) { // RNE
    unsigned u = __float_as_uint(f);
    return (unsigned short)((u + 0x7fffu + ((u >> 16) & 1u)) >> 16);
}
__device__ __forceinline__ void ld8(const float* p, float* f) {
    float4 a = *(const float4*)p, b = *(const float4*)(p + 4);
    f[0]=a.x; f[1]=a.y; f[2]=a.z; f[3]=a.w; f[4]=b.x; f[5]=b.y; f[6]=b.z; f[7]=b.w;
}
__device__ __forceinline__ uint4 pack8(const float* f, float scale) {
    union { uint4 v; unsigned short s[8]; } w;
    #pragma unroll
    for (int j = 0; j < 8; j++) w.s[j] = f2bf(f[j] * scale);
    return w.v;
}
// combine high-16s of two floats into one dword: [lo16=a.hi16, hi16=b.hi16]
__device__ __forceinline__ unsigned packhi(float a, float b) {
#if __has_builtin(__builtin_amdgcn_perm)
    return __builtin_amdgcn_perm(__float_as_uint(b), __float_as_uint(a), 0x07060302u);
#else
    return (__float_as_uint(a) >> 16) | (__float_as_uint(b) & 0xffff0000u);
#endif
}

// ---- pre-pass: per block (st, bh): V 64x64 tile -> bf16 V^T tile, plus a
// 4096-elem chunk of Q (scaled) and K -> bf16.
__global__ __launch_bounds__(256) void prep(
    const float* __restrict__ Qf, const float* __restrict__ Kf,
    const float* __restrict__ Vf, unsigned short* __restrict__ qb,
    unsigned short* __restrict__ kb, unsigned short* __restrict__ vtb)
{
    const int st = blockIdx.x, bh = blockIdx.y;
    __shared__ unsigned lt32[64][LDP / 2];   // dword view: 36 dwords/row
    const float* vp = Vf + ((size_t)bh * S_LEN + st * 64) * DHDIM;
    {
        const int c = threadIdx.x;
        const int sp = c >> 3;            // s-pair index 0..31
        const int d0 = (c & 7) * 8;
        float fa[8], fb[8];
        ld8(vp + (2 * sp) * DHDIM + d0, fa);
        ld8(vp + (2 * sp + 1) * DHDIM + d0, fb);
        #pragma unroll
        for (int j = 0; j < 8; j++) {
            int d = d0 + j;
            int colw = (sp & 3) | ((((sp >> 2) ^ (d >> 3)) & 7) << 2);
            lt32[d][colw] = (unsigned)f2bf(fa[j]) | ((unsigned)f2bf(fb[j]) << 16);
        }
    }
    size_t off = ((size_t)(bh * 32 + st) * 4096) + (size_t)threadIdx.x * 16;
    float f[8];
    ld8(Qf + off, f);     *(uint4*)(qb + off)     = pack8(f, QSCALE);
    ld8(Qf + off + 8, f); *(uint4*)(qb + off + 8) = pack8(f, QSCALE);
    ld8(Kf + off, f);     *(uint4*)(kb + off)     = pack8(f, 1.0f);
    ld8(Kf + off + 8, f); *(uint4*)(kb + off + 8) = pack8(f, 1.0f);
    __syncthreads();
    unsigned short* op = vtb + (size_t)bh * DHDIM * S_LEN + st * 64;
    for (int c = threadIdx.x; c < 512; c += 256) {
        int d = c >> 3, q = c & 7;
        int colw = ((q ^ (d >> 3)) & 7) << 2;
        *(uint4*)(op + (size_t)d * S_LEN + q * 8) = *(const uint4*)&lt32[d][colw];
    }
}

// ---- main: block = (bh, rank). 2-tile windows, double-buffered K/V regions.
__global__ __launch_bounds__(256) void fattn_splitk(
    const unsigned short* __restrict__ Qp, const unsigned short* __restrict__ Kp,
    const unsigned short* __restrict__ Vp,
    float* __restrict__ pO, float* __restrict__ pL, float* __restrict__ O)
{
    __shared__ unsigned short smem[320 * LDP]; // 46.1 KB -> 3 blocks/CU
    unsigned short (*ksA)[LDP]  = (unsigned short(*)[LDP])smem;
    unsigned short (*ksB)[LDP]  = (unsigned short(*)[LDP])(smem + 64 * LDP);
    unsigned short (*vtsA)[LDP] = (unsigned short(*)[LDP])(smem + 128 * LDP);
    unsigned short (*vtsB)[LDP] = (unsigned short(*)[LDP])(smem + 192 * LDP);
    unsigned short (*qs)[LDP]   = (unsigned short(*)[LDP])(smem + 256 * LDP);
    unsigned short (*pst)[LDP]  = qs; // overlay: wave w touches only rows w*16..+15

    const int bh   = blockIdx.x;           // 0..31
    const unsigned e = RTAB[blockIdx.y];   // 0..62, longest-first
    const int qt   = e >> 24;
    const int k0   = (e >> 16) & 255;
    const int k1   = (e >> 8) & 255;
    const int sl   = e & 255;
    const bool whole = (sl == 255);

    const int tid = threadIdx.x;
    const int wave = tid >> 6, lane = tid & 63;
    const int quad = lane >> 4, l16 = lane & 15;

    // ---- stage Q tile (bf16, pre-scaled by prep)
    {
        const unsigned short* src = Qp + ((size_t)bh * S_LEN + qt * 64) * DHDIM;
        for (int c = tid; c < 512; c += 256) {
            int row = c >> 3, c8 = (c & 7) * 8;
            *(uint4*)&qs[row][c8] = *(const uint4*)(src + row * DHDIM + c8);
        }
    }
    __syncthreads();

    const int prow = wave * 16 + l16; // this lane's q-row (transposed scheme)
    const bf16x8 bq0 = *(const bf16x8*)&qs[prow][quad * 8];
    const bf16x8 bq1 = *(const bf16x8*)&qs[prow][32 + quad * 8];

    bf16x8 ones;
    #pragma unroll
    for (int j = 0; j < 8; j++) ones[j] = (short)0x3F80; // bf16 1.0

    f32x4 of[4];
    f32x4 of_l = (f32x4){0.f, 0.f, 0.f, 0.f}; // ones-row * Pt = l per q-col
    #pragma unroll
    for (int n = 0; n < 4; n++) of[n] = (f32x4){0.f, 0.f, 0.f, 0.f};

    // ---- register prefetch for a PAIR of K/V tiles
    const unsigned short* Kbh = Kp + (size_t)bh * S_LEN * DHDIM;
    const unsigned short* Vbh = Vp + (size_t)bh * DHDIM * S_LEN;
    const int sr = tid >> 3, sc = (tid & 7) * 8;   // staging rows sr, sr+32
    uint4 krA0, krA1, vrA0, vrA1, krB0, krB1, vrB0, vrB1;
    {
        const unsigned short* ksrc = Kbh + (size_t)k0 * 64 * DHDIM;
        const unsigned short* vsrc = Vbh + k0 * 64;
        krA0 = *(const uint4*)(ksrc + sr * DHDIM + sc);
        krA1 = *(const uint4*)(ksrc + (sr + 32) * DHDIM + sc);
        vrA0 = *(const uint4*)(vsrc + (size_t)sr * S_LEN + sc);
        vrA1 = *(const uint4*)(vsrc + (size_t)(sr + 32) * S_LEN + sc);
    }
    if (k0 + 1 < k1) {
        const unsigned short* ksrc = Kbh + (size_t)(k0 + 1) * 64 * DHDIM;
        const unsigned short* vsrc = Vbh + (k0 + 1) * 64;
        krB0 = *(const uint4*)(ksrc + sr * DHDIM + sc);
        krB1 = *(const uint4*)(ksrc + (sr + 32) * DHDIM + sc);
        vrB0 = *(const uint4*)(vsrc + (size_t)sr * S_LEN + sc);
        vrB1 = *(const uint4*)(vsrc + (size_t)(sr + 32) * S_LEN + sc);
    }

    for (int kt = k0; kt < k1; kt += 2) {
        const bool hasB = (kt + 1 < k1);
        __syncthreads(); // prior window done reading ksA/B, vtsA/B

        // write current prefetched pair to LDS
        *(uint4*)&ksA[sr][sc]       = krA0;
        *(uint4*)&ksA[sr + 32][sc]  = krA1;
        *(uint4*)&vtsA[sr][sc]      = vrA0;
        *(uint4*)&vtsA[sr + 32][sc] = vrA1;
        if (hasB) {
            *(uint4*)&ksB[sr][sc]       = krB0;
            *(uint4*)&ksB[sr + 32][sc]  = krB1;
            *(uint4*)&vtsB[sr][sc]      = vrB0;
            *(uint4*)&vtsB[sr + 32][sc] = vrB1;
        }

        // issue next pair's global loads; latency hides under this window
        if (kt + 2 < k1) {
            const unsigned short* ksrc = Kbh + (size_t)(kt + 2) * 64 * DHDIM;
            const unsigned short* vsrc = Vbh + (kt + 2) * 64;
            krA0 = *(const uint4*)(ksrc + sr * DHDIM + sc);
            krA1 = *(const uint4*)(ksrc + (sr + 32) * DHDIM + sc);
            vrA0 = *(const uint4*)(vsrc + (size_t)sr * S_LEN + sc);
            vrA1 = *(const uint4*)(vsrc + (size_t)(sr + 32) * S_LEN + sc);
        }
        if (kt + 3 < k1) {
            const unsigned short* ksrc = Kbh + (size_t)(kt + 3) * 64 * DHDIM;
            const unsigned short* vsrc = Vbh + (kt + 3) * 64;
            krB0 = *(const uint4*)(ksrc + sr * DHDIM + sc);
            krB1 = *(const uint4*)(ksrc + (sr + 32) * DHDIM + sc);
            vrB0 = *(const uint4*)(vsrc + (size_t)sr * S_LEN + sc);
            vrB1 = *(const uint4*)(vsrc + (size_t)(sr + 32) * S_LEN + sc);
        }
        __syncthreads();

        // ---- St for BOTH tiles first: 16 independent MFMAs; St_B fills
        // softmax-A / fence stalls below.
        __builtin_amdgcn_s_setprio(1);
        f32x4 sfA[4], sfB[4];
        #pragma unroll
        for (int n = 0; n < 4; n++) {
            bf16x8 ak0 = *(const bf16x8*)&ksA[n * 16 + l16][quad * 8];
            bf16x8 ak1 = *(const bf16x8*)&ksA[n * 16 + l16][32 + quad * 8];
            sfA[n] = (f32x4){-M2, -M2, -M2, -M2};
            sfA[n] = __builtin_amdgcn_mfma_f32_16x16x32_bf16(ak0, bq0, sfA[n], 0, 0, 0);
            sfA[n] = __builtin_amdgcn_mfma_f32_16x16x32_bf16(ak1, bq1, sfA[n], 0, 0, 0);
        }
        if (hasB) {
            #pragma unroll
            for (int n = 0; n < 4; n++) {
                bf16x8 bk0 = *(const bf16x8*)&ksB[n * 16 + l16][quad * 8];
                bf16x8 bk1 = *(const bf16x8*)&ksB[n * 16 + l16][32 + quad * 8];
                sfB[n] = (f32x4){-M2, -M2, -M2, -M2};
                sfB[n] = __builtin_amdgcn_mfma_f32_16x16x32_bf16(bk0, bq0, sfB[n], 0, 0, 0);
                sfB[n] = __builtin_amdgcn_mfma_f32_16x16x32_bf16(bk1, bq1, sfB[n], 0, 0, 0);
            }
        }
        __builtin_amdgcn_s_setprio(0);

        // ---- tile A: softmax -> pst -> fence -> PV
        {
            const bool diag = (kt == qt);
            #pragma unroll
            for (int n = 0; n < 4; n++) {
                float p[4];
                #pragma unroll
                for (int r = 0; r < 4; r++) {
                    p[r] = fast_exp2(sfA[n][r]);
                    if (diag && (n * 16 + quad * 4 + r > prow)) p[r] = 0.f;
                }
                uint2 dw;
                dw.x = packhi(p[0], p[1]); // bf16 truncation via byte-select
                dw.y = packhi(p[2], p[3]);
                *(uint2*)&pst[prow][n * 16 + quad * 4] = dw;
            }
            asm volatile("s_waitcnt lgkmcnt(0)" ::: "memory"); // wave-local fence

            __builtin_amdgcn_s_setprio(1);
            bf16x8 bp0 = *(const bf16x8*)&pst[prow][quad * 8];
            bf16x8 bp1 = *(const bf16x8*)&pst[prow][32 + quad * 8];
            of_l = __builtin_amdgcn_mfma_f32_16x16x32_bf16(ones, bp0, of_l, 0, 0, 0);
            of_l = __builtin_amdgcn_mfma_f32_16x16x32_bf16(ones, bp1, of_l, 0, 0, 0);
            #pragma unroll
            for (int n = 0; n < 4; n++) {
                bf16x8 av0 = *(const bf16x8*)&vtsA[n * 16 + l16][quad * 8];
                bf16x8 av1 = *(const bf16x8*)&vtsA[n * 16 + l16][32 + quad * 8];
                of[n] = __builtin_amdgcn_mfma_f32_16x16x32_bf16(av0, bp0, of[n], 0, 0, 0);
                of[n] = __builtin_amdgcn_mfma_f32_16x16x32_bf16(av1, bp1, of[n], 0, 0, 0);
            }
            __builtin_amdgcn_s_setprio(0);
        }

        // ---- tile B: softmax -> pst (wave-local rows reuse, no barrier
        // needed: the lgkmcnt(0) below orders our own reads-before-writes)
        if (hasB) {
            const bool diag = (kt + 1 == qt);
            #pragma unroll
            for (int n = 0; n < 4; n++) {
                float p[4];
                #pragma unroll
                for (int r = 0; r < 4; r++) {
                    p[r] = fast_exp2(sfB[n][r]);
                    if (diag && (n * 16 + quad * 4 + r > prow)) p[r] = 0.f;
                }
                uint2 dw;
                dw.x = packhi(p[0], p[1]);
                dw.y = packhi(p[2], p[3]);
                *(uint2*)&pst[prow][n * 16 + quad * 4] = dw;
            }
            asm volatile("s_waitcnt lgkmcnt(0)" ::: "memory");

            __builtin_amdgcn_s_setprio(1);
            bf16x8 bp0 = *(const bf16x8*)&pst[prow][quad * 8];
            bf16x8 bp1 = *(const bf16x8*)&pst[prow][32 + quad * 8];
            of_l = __builtin_amdgcn_mfma_f32_16x16x32_bf16(ones, bp0, of_l, 0, 0, 0);
            of_l = __builtin_amdgcn_mfma_f32_16x16x32_bf16(ones, bp1, of_l, 0, 0, 0);
            #pragma unroll
            for (int n = 0; n < 4; n++) {
                bf16x8 av0 = *(const bf16x8*)&vtsB[n * 16 + l16][quad * 8];
                bf16x8 av1 = *(const bf16x8*)&vtsB[n * 16 + l16][32 + quad * 8];
                of[n] = __builtin_amdgcn_mfma_f32_16x16x32_bf16(av0, bp0, of[n], 0, 0, 0);
                of[n] = __builtin_amdgcn_mfma_f32_16x16x32_bf16(av1, bp1, of[n], 0, 0, 0);
            }
            __builtin_amdgcn_s_setprio(0);
        }
    }

    if (whole) {
        // short row: normalize and write O directly, no partial traffic
        const float inv = 1.f / of_l[0];
        float* op = O + ((size_t)bh * S_LEN + qt * 64 + prow) * DHDIM;
        #pragma unroll
        for (int n = 0; n < 4; n++)
            *(float4*)(op + n * 16 + quad * 4) = make_float4(
                of[n][0] * inv, of[n][1] * inv, of[n][2] * inv, of[n][3] * inv);
    } else {
        // piece: write unnormalized partial + per-row l (fixed-max softmax
        // => partials combine exactly by summation in the combine kernel)
        const int slot = bh * NSLOT + sl;
        if (quad == 0) pL[slot * 64 + prow] = of_l[0];
        float* op = pO + (size_t)slot * 4096 + prow * 64;
        #pragma unroll
        for (int n = 0; n < 4; n++)
            *(float4*)(op + n * 16 + quad * 4) =
                make_float4(of[n][0], of[n][1], of[n][2], of[n][3]);
    }
}

// ---- combine: O = sum(Oi) / sum(li), per (bh, qt) for qt in [11,31]
__global__ __launch_bounds__(256) void combine(
    const float* __restrict__ pO, const float* __restrict__ pL,
    float* __restrict__ O)
{
    const int qt = 11 + blockIdx.x, bh = blockIdx.y;
    int base, cnt;
    if (qt < 22) { base = (qt - 11) * 2;      cnt = 2; }
    else         { base = 22 + 3 * (qt - 22); cnt = 3; }
    const int sb = bh * NSLOT + base;
    const float* A = pO + (size_t)sb * 4096;
    float* out = O + ((size_t)bh * S_LEN + qt * 64) * DHDIM;
    #pragma unroll
    for (int k = 0; k < 4; k++) {
        int c = threadIdx.x + k * 256;     // float4 chunk 0..1023
        int row = c >> 4;
        float l = pL[sb * 64 + row] + pL[(sb + 1) * 64 + row];
        float4 a = *(const float4*)(A + c * 4);
        float4 b = *(const float4*)(A + 4096 + c * 4);
        float4 s = make_float4(a.x + b.x, a.y + b.y, a.z + b.z, a.w + b.w);
        if (cnt == 3) {
            l += pL[(sb + 2) * 64 + row];
            float4 d = *(const float4*)(A + 8192 + c * 4);
            s = make_float4(s.x + d.x, s.y + d.y, s.z + d.z, s.w + d.w);
        }
        float inv = 1.f / l;
        *(float4*)(out + c * 4) = make_float4(
            s.x * inv, s.y * inv, s.z * inv, s.w * inv);
    }
}

// ---- fallback kernels (whole-row blocks), used when ws too small
template <bool PRE>
__global__ __launch_bounds__(256) void fattn_kernel(
    const void* __restrict__ Qp, const void* __restrict__ Kp,
    const void* __restrict__ Vp, float* __restrict__ O)
{
    __shared__ unsigned short smem[192 * LDP];
    unsigned short (*ks)[LDP]  = (unsigned short(*)[LDP])smem;
    unsigned short (*vts)[LDP] = (unsigned short(*)[LDP])(smem + 64 * LDP);
    unsigned short (*qs)[LDP]  = (unsigned short(*)[LDP])(smem + 128 * LDP);
    unsigned short (*pst)[LDP] = qs;

    const int id = blockIdx.y * 32 + blockIdx.x;
    const int g  = id >> 8;
    const int r8 = id & 255;
    const int bh = r8 >> 3;
    const int s8 = r8 & 7;
    const int qt = (g == 0) ? 31 - 2 * s8 : (g == 1) ? 2 * s8
                 : (g == 2) ? 30 - 2 * s8 : 2 * s8 + 1;

    const int tid = threadIdx.x;
    const int wave = tid >> 6, lane = tid & 63;
    const int quad = lane >> 4, l16 = lane & 15;

    if constexpr (PRE) {
        const unsigned short* src = (const unsigned short*)Qp
            + ((size_t)bh * S_LEN + qt * 64) * DHDIM;
        for (int c = tid; c < 512; c += 256) {
            int row = c >> 3, c8 = (c & 7) * 8;
            *(uint4*)&qs[row][c8] = *(const uint4*)(src + row * DHDIM + c8);
        }
    } else {
        const float* src = (const float*)Qp + ((size_t)bh * S_LEN + qt * 64) * DHDIM;
        for (int c = tid; c < 512; c += 256) {
            int row = c >> 3, c8 = (c & 7) * 8;
            float f[8]; ld8(src + row * DHDIM + c8, f);
            *(uint4*)&qs[row][c8] = pack8(f, QSCALE);
        }
    }
    __syncthreads();

    const int prow = wave * 16 + l16;
    const bf16x8 bq0 = *(const bf16x8*)&qs[prow][quad * 8];
    const bf16x8 bq1 = *(const bf16x8*)&qs[prow][32 + quad * 8];

    float l_p = 0.f;
    f32x4 of[4];
    #pragma unroll
    for (int n = 0; n < 4; n++) of[n] = (f32x4){0.f, 0.f, 0.f, 0.f};

    for (int kt = 0; kt <= qt; kt++) {
        __syncthreads();
        if constexpr (PRE) {
            const unsigned short* ksrc = (const unsigned short*)Kp
                + ((size_t)bh * S_LEN + kt * 64) * DHDIM;
            const unsigned short* vsrc = (const unsigned short*)Vp
                + (size_t)bh * DHDIM * S_LEN + kt * 64;
            for (int c = tid; c < 512; c += 256) {
                int row = c >> 3, c8 = (c & 7) * 8;
                *(uint4*)&ks[row][c8]  = *(const uint4*)(ksrc + row * DHDIM + c8);
                *(uint4*)&vts[row][c8] = *(const uint4*)(vsrc + (size_t)row * S_LEN + c8);
            }
        } else {
            const float* ksrc = (const float*)Kp + ((size_t)bh * S_LEN + kt * 64) * DHDIM;
            const float* vsrc = (const float*)Vp + ((size_t)bh * S_LEN + kt * 64) * DHDIM;
            for (int c = tid; c < 512; c += 256) {
                int row = c >> 3, c8 = (c & 7) * 8;
                float f[8];
                ld8(ksrc + row * DHDIM + c8, f);
                *(uint4*)&ks[row][c8] = pack8(f, 1.0f);
                ld8(vsrc + row * DHDIM + c8, f);
                #pragma unroll
                for (int j = 0; j < 8; j++) vts[c8 + j][row] = f2bf(f[j]);
            }
        }
        __syncthreads();

        f32x4 sf[4];
        #pragma unroll
        for (int n = 0; n < 4; n++) {
            bf16x8 ak0 = *(const bf16x8*)&ks[n * 16 + l16][quad * 8];
            bf16x8 ak1 = *(const bf16x8*)&ks[n * 16 + l16][32 + quad * 8];
            sf[n] = (f32x4){-M2, -M2, -M2, -M2};
            sf[n] = __builtin_amdgcn_mfma_f32_16x16x32_bf16(ak0, bq0, sf[n], 0, 0, 0);
            sf[n] = __builtin_amdgcn_mfma_f32_16x16x32_bf16(ak1, bq1, sf[n], 0, 0, 0);
        }

        const bool diag = (kt == qt);
        #pragma unroll
        for (int n = 0; n < 4; n++) {
            float p[4];
            #pragma unroll
            for (int r = 0; r < 4; r++) {
                p[r] = fast_exp2(sf[n][r]);
                if (diag && (n * 16 + quad * 4 + r > prow)) p[r] = 0.f;
                l_p += p[r];
            }
            uint2 dw;
            dw.x = packhi(p[0], p[1]);
            dw.y = packhi(p[2], p[3]);
            *(uint2*)&pst[prow][n * 16 + quad * 4] = dw;
        }
        asm volatile("s_waitcnt lgkmcnt(0)" ::: "memory");

        bf16x8 bp0 = *(const bf16x8*)&pst[prow][quad * 8];
        bf16x8 bp1 = *(const bf16x8*)&pst[prow][32 + quad * 8];
        #pragma unroll
        for (int n = 0; n < 4; n++) {
            bf16x8 av0 = *(const bf16x8*)&vts[n * 16 + l16][quad * 8];
            bf16x8 av1 = *(const bf16x8*)&vts[n * 16 + l16][32 + quad * 8];
            of[n] = __builtin_amdgcn_mfma_f32_16x16x32_bf16(av0, bp0, of[n], 0, 0, 0);
            of[n] = __builtin_amdgcn_mfma_f32_16x16x32_bf16(av1, bp1, of[n], 0, 0, 0);
        }
    }

    l_p += __shfl_xor(l_p, 16);
    l_p += __shfl_xor(l_p, 32);
    const float inv = 1.f / l_p;
    float* op = O + ((size_t)bh * S_LEN + qt * 64 + prow) * DHDIM;
    #pragma unroll
    for (int n = 0; n < 4; n++)
        *(float4*)(op + n * 16 + quad * 4) = make_float4(
            of[n][0] * inv, of[n][1] * inv, of[n][2] * inv, of[n][3] * inv);
}

extern "C" void kernel_launch(void* const* d_in, const int* in_sizes, int n_in,
                              void* d_out, int out_size, void* d_ws, size_t ws_size,
                              hipStream_t stream) {
    const float* Q = (const float*)d_in[0];
    const float* K = (const float*)d_in[1];
    const float* V = (const float*)d_in[2];
    // d_in[3] = causal mask: analytic, not read.
    float* O = (float*)d_out;
    const size_t N = (size_t)NHEADS * S_LEN * DHDIM;      // 4,194,304 elems
    const size_t prepB  = 3 * N * sizeof(unsigned short); // 25.2 MB
    // 52 partial slots per bh (qt>=11 pieces): O-partials + l
    const size_t partB  = (size_t)NSLOT * 32 * (4096 + 64) * sizeof(float); // 27.7 MB

    if (d_ws && ws_size >= prepB + partB) {
        unsigned short* qb  = (unsigned short*)d_ws;
        unsigned short* kb  = qb + N;
        unsigned short* vtb = kb + N;
        float* pO = (float*)((char*)d_ws + prepB);
        float* pL = pO + (size_t)NSLOT * 32 * 4096;
        prep<<<dim3(S_LEN / 64, NHEADS), 256, 0, stream>>>(Q, K, V, qb, kb, vtb);
        fattn_splitk<<<dim3(32, 63), 256, 0, stream>>>(qb, kb, vtb, pO, pL, O);
        combine<<<dim3(21, 32), 256, 0, stream>>>(pO, pL, O);
    } else if (d_ws && ws_size >= prepB) {
        unsigned short* qb  = (unsigned short*)d_ws;
        unsigned short* kb  = qb + N;
        unsigned short* vtb = kb + N;
        prep<<<dim3(S_LEN / 64, NHEADS), 256, 0, stream>>>(Q, K, V, qb, kb, vtb);
        fattn_kernel<true><<<dim3(32, 32), 256, 0, stream>>>(qb, kb, vtb, O);
    } else {
        fattn_kernel<false><<<dim3(32, 32), 256, 0, stream>>>(Q, K, V, O);
    }
}

// Round 9
// 141.705 us; speedup vs baseline: 1.1693x; 1.0212x over previous
//
#include <hip/hip_runtime.h>

// Causal MHA: B=2, H=16, S=2048, DH=64. fp32 in/out. bf16 MFMA inside.
// R18: 32x32 MFMA fragments to kill LDS read duplication.
// Cost model fitted over R12/R15/R17 (all ~43.5us): per 64x64 tile-op the
// 16x16 prow scheme moves ~96 b128-equiv through LDS (~30us/CU) + 6M
// conflict-cycles (~10us) ~= measured 43us. Occupancy proven irrelevant
// (24% vs 35%, same time). Fix: v_mfma_f32_32x32x16_bf16 -- each wave owns
// one 32x32 quadrant: K/V A-frags read ONCE per wave (LDS 96->72/tile-op,
// MFMA instrs halve at same FLOPs). P crosses waves via LDS, software-
// pipelined: iter t = {bar; stage KV(t); write P(t-1); prefetch t+1; bar;
// PV(t-1) || St(t); exp2->pdw regs}. vts & pst double-buffered; 46KB LDS,
// 3 blocks/CU (R17 proved harmless). D-layout (col=lane&31, row=(reg&3)+
// 8(reg>>2)+4(lane>>5)) is HW-verified; A/B by analogy with the 16x16
// layout this kernel family already exploits. l via all-ones-A MFMA
// (layout-assumption-immune). Scheduling/RTAB/combine/prep = R15 verbatim.

#define S_LEN  2048
#define DHDIM  64
#define NHEADS 32   // B*H
#define LDP    72   // padded LDS row length in shorts (144B = 9*16B)
#define M2     23.083120654223414f   // 16 * log2(e)
#define QSCALE 0.18033688011117658f  // 0.125 * log2(e)
#define NSLOT  52   // partial slots per bh

typedef __attribute__((ext_vector_type(8))) short bf16x8;
typedef __attribute__((ext_vector_type(4))) float f32x4;
typedef __attribute__((ext_vector_type(16))) float f32x16;

// rank table: 63 items per bh, LPT (desc length) order.
// entry = qt<<24 | k0<<16 | k1<<8 | slot  (slot 255 = whole row, direct O)
#define RT(qt,k0,k1,sl) ((unsigned)(qt)<<24 | (unsigned)(k0)<<16 | (unsigned)(k1)<<8 | (unsigned)(sl))
__device__ __constant__ unsigned RTAB[63] = {
    RT(31,0,11,49),  RT(31,11,22,50), RT(30,0,11,46),  RT(21,0,11,20),
    RT(21,11,22,21), RT(20,0,11,18),  RT(10,0,11,255),
    RT(31,22,32,51), RT(30,11,21,47), RT(30,21,31,48), RT(29,0,10,43),
    RT(29,10,20,44), RT(29,20,30,45), RT(28,0,10,40),  RT(28,10,20,41),
    RT(27,0,10,37),  RT(20,11,21,19), RT(19,0,10,16),  RT(19,10,20,17),
    RT(18,0,10,14),  RT(9,0,10,255),
    RT(28,20,29,42), RT(27,10,19,38), RT(27,19,28,39), RT(26,0,9,34),
    RT(26,9,18,35),  RT(26,18,27,36), RT(25,0,9,31),   RT(25,9,18,32),
    RT(24,0,9,28),   RT(18,10,19,15), RT(17,0,9,12),   RT(17,9,18,13),
    RT(16,0,9,10),   RT(8,0,9,255),
    RT(25,18,26,33), RT(24,9,17,29),  RT(24,17,25,30), RT(23,0,8,25),
    RT(23,8,16,26),  RT(23,16,24,27), RT(22,0,8,22),   RT(22,8,16,23),
    RT(16,9,17,11),  RT(15,0,8,8),    RT(15,8,16,9),   RT(14,0,8,6),
    RT(7,0,8,255),
    RT(22,16,23,24), RT(14,8,15,7),   RT(13,0,7,4),    RT(13,7,14,5),
    RT(12,0,7,2),    RT(6,0,7,255),
    RT(12,7,13,3),   RT(11,0,6,0),    RT(11,6,12,1),   RT(5,0,6,255),
    RT(4,0,5,255),   RT(3,0,4,255),   RT(2,0,3,255),   RT(1,0,2,255),
    RT(0,0,1,255)};

__device__ __forceinline__ float fast_exp2(float x) {
#if __has_builtin(__builtin_amdgcn_exp2f)
    return __builtin_amdgcn_exp2f(x);
#else
    return exp2f(x);
#endif
}
__device__ __forceinline__ unsigned short f2bf(float f) { // RNE
    unsigned u = __float_as_uint(f);
    return (unsigned short)((u + 0x7fffu + ((u >> 16) & 1u)) >> 16);
}
__device__ __forceinline__ void ld8(const float* p, float* f) {
    float4 a = *(const float4*)p, b = *(const float4*)(p + 4);
    f[0]=a.x; f[1]=a.y; f[2]=a.z; f[3]=a.w; f[4]=b.x; f[5]=b.y; f[6]=b.z; f[7]=b.w;
}
__device__ __forceinline__ uint4 pack8(const float* f, float scale) {
    union { uint4 v; unsigned short s[8]; } w;
    #pragma unroll
    for (int j = 0; j < 8; j++) w.s[j] = f2bf(f[j] * scale);
    return w.v;
}
// combine high-16s of two floats into one dword: [lo16=a.hi16, hi16=b.hi16]
__device__ __forceinline__ unsigned packhi(float a, float b) {
#if __has_builtin(__builtin_amdgcn_perm)
    return __builtin_amdgcn_perm(__float_as_uint(b), __float_as_uint(a), 0x07060302u);
#else
    return (__float_as_uint(a) >> 16) | (__float_as_uint(b) & 0xffff0000u);
#endif
}

// ---- pre-pass: per block (st, bh): V 64x64 tile -> bf16 V^T tile, plus a
// 4096-elem chunk of Q (scaled) and K -> bf16.
__global__ __launch_bounds__(256) void prep(
    const float* __restrict__ Qf, const float* __restrict__ Kf,
    const float* __restrict__ Vf, unsigned short* __restrict__ qb,
    unsigned short* __restrict__ kb, unsigned short* __restrict__ vtb)
{
    const int st = blockIdx.x, bh = blockIdx.y;
    __shared__ unsigned lt32[64][LDP / 2];   // dword view: 36 dwords/row
    const float* vp = Vf + ((size_t)bh * S_LEN + st * 64) * DHDIM;
    {
        const int c = threadIdx.x;
        const int sp = c >> 3;            // s-pair index 0..31
        const int d0 = (c & 7) * 8;
        float fa[8], fb[8];
        ld8(vp + (2 * sp) * DHDIM + d0, fa);
        ld8(vp + (2 * sp + 1) * DHDIM + d0, fb);
        #pragma unroll
        for (int j = 0; j < 8; j++) {
            int d = d0 + j;
            int colw = (sp & 3) | ((((sp >> 2) ^ (d >> 3)) & 7) << 2);
            lt32[d][colw] = (unsigned)f2bf(fa[j]) | ((unsigned)f2bf(fb[j]) << 16);
        }
    }
    size_t off = ((size_t)(bh * 32 + st) * 4096) + (size_t)threadIdx.x * 16;
    float f[8];
    ld8(Qf + off, f);     *(uint4*)(qb + off)     = pack8(f, QSCALE);
    ld8(Qf + off + 8, f); *(uint4*)(qb + off + 8) = pack8(f, QSCALE);
    ld8(Kf + off, f);     *(uint4*)(kb + off)     = pack8(f, 1.0f);
    ld8(Kf + off + 8, f); *(uint4*)(kb + off + 8) = pack8(f, 1.0f);
    __syncthreads();
    unsigned short* op = vtb + (size_t)bh * DHDIM * S_LEN + st * 64;
    for (int c = threadIdx.x; c < 512; c += 256) {
        int d = c >> 3, q = c & 7;
        int colw = ((q ^ (d >> 3)) & 7) << 2;
        *(uint4*)(op + (size_t)d * S_LEN + q * 8) = *(const uint4*)&lt32[d][colw];
    }
}

// ---- main: block = (bh, rank). 4 waves = (kh/dh, qh) 32x32 quadrants.
__global__ __launch_bounds__(256, 3) void fattn_splitk(
    const unsigned short* __restrict__ Qp, const unsigned short* __restrict__ Kp,
    const unsigned short* __restrict__ Vp,
    float* __restrict__ pO, float* __restrict__ pL, float* __restrict__ O)
{
    __shared__ unsigned short smem[320 * LDP]; // ks | vtsA | vtsB | pstA | pstB
    unsigned short (*ks)[LDP]   = (unsigned short(*)[LDP])smem;
    unsigned short (*vtsA)[LDP] = (unsigned short(*)[LDP])(smem + 64 * LDP);
    unsigned short (*vtsB)[LDP] = (unsigned short(*)[LDP])(smem + 128 * LDP);
    unsigned short (*pstA)[LDP] = (unsigned short(*)[LDP])(smem + 192 * LDP);
    unsigned short (*pstB)[LDP] = (unsigned short(*)[LDP])(smem + 256 * LDP);

    const int bh   = blockIdx.x;           // 0..31
    const unsigned e = RTAB[blockIdx.y];   // 0..62, longest-first
    const int qt   = e >> 24;
    const int k0   = (e >> 16) & 255;
    const int k1   = (e >> 8) & 255;
    const int sl   = e & 255;
    const bool whole = (sl == 255);

    const int tid  = threadIdx.x;
    const int wave = tid >> 6, lane = tid & 63;
    const int q31  = lane & 31, hi = lane >> 5;
    const int qh   = wave & 1, kh = wave >> 1;   // kh doubles as dh for PV
    const int qrow = qh * 32 + q31;              // local q row 0..63

    // ---- Q B-fragments, direct from global (pre-scaled bf16 from prep)
    const unsigned short* qsrc = Qp + ((size_t)bh * S_LEN + qt * 64 + qrow) * DHDIM;
    const bf16x8 bq0 = *(const bf16x8*)(qsrc + hi * 8);
    const bf16x8 bq1 = *(const bf16x8*)(qsrc + 16 + hi * 8);
    const bf16x8 bq2 = *(const bf16x8*)(qsrc + 32 + hi * 8);
    const bf16x8 bq3 = *(const bf16x8*)(qsrc + 48 + hi * 8);

    bf16x8 ones;
    #pragma unroll
    for (int j = 0; j < 8; j++) ones[j] = (short)0x3F80; // bf16 1.0

    f32x16 of, ofl;
    #pragma unroll
    for (int i = 0; i < 16; i++) { of[i] = 0.f; ofl[i] = 0.f; }
    unsigned pdw[8];   // packed P of tile t (8 dwords), carried across bar

    // ---- staging + prefetch (R12 scheme)
    const unsigned short* Kbh = Kp + (size_t)bh * S_LEN * DHDIM;
    const unsigned short* Vbh = Vp + (size_t)bh * DHDIM * S_LEN;
    const int sr = tid >> 3, sc = (tid & 7) * 8;
    uint4 kr0, kr1, vr0, vr1;
    {
        const unsigned short* ksrc = Kbh + (size_t)k0 * 64 * DHDIM;
        const unsigned short* vsrc = Vbh + k0 * 64;
        kr0 = *(const uint4*)(ksrc + sr * DHDIM + sc);
        kr1 = *(const uint4*)(ksrc + (sr + 32) * DHDIM + sc);
        vr0 = *(const uint4*)(vsrc + (size_t)sr * S_LEN + sc);
        vr1 = *(const uint4*)(vsrc + (size_t)(sr + 32) * S_LEN + sc);
    }

    for (int kt = k0; kt < k1; kt++) {
        __syncthreads();  // (a) all waves done with ks(t-1), vts(t-2), pst reads

        *(uint4*)&ks[sr][sc]      = kr0;
        *(uint4*)&ks[sr + 32][sc] = kr1;
        {
            unsigned short (*vts)[LDP] = (kt & 1) ? vtsB : vtsA;
            *(uint4*)&vts[sr][sc]      = vr0;
            *(uint4*)&vts[sr + 32][sc] = vr1;
        }
        if (kt > k0) {  // publish P(kt-1)
            unsigned short (*pst)[LDP] = ((kt - 1) & 1) ? pstB : pstA;
            const int cb = kh * 32 + 4 * hi;
            *(uint2*)&pst[qrow][cb +  0] = *(uint2*)&pdw[0];
            *(uint2*)&pst[qrow][cb +  8] = *(uint2*)&pdw[2];
            *(uint2*)&pst[qrow][cb + 16] = *(uint2*)&pdw[4];
            *(uint2*)&pst[qrow][cb + 24] = *(uint2*)&pdw[6];
        }
        if (kt + 1 < k1) {  // prefetch next tile
            const unsigned short* ksrc = Kbh + (size_t)(kt + 1) * 64 * DHDIM;
            const unsigned short* vsrc = Vbh + (kt + 1) * 64;
            kr0 = *(const uint4*)(ksrc + sr * DHDIM + sc);
            kr1 = *(const uint4*)(ksrc + (sr + 32) * DHDIM + sc);
            vr0 = *(const uint4*)(vsrc + (size_t)sr * S_LEN + sc);
            vr1 = *(const uint4*)(vsrc + (size_t)(sr + 32) * S_LEN + sc);
        }
        __syncthreads();  // (b) KV(kt) and P(kt-1) visible

        // ---- PV(kt-1): O-quadrant (dh=kh, qh), K=64 via 4 K=16 steps
        if (kt > k0) {
            const unsigned short (*pst)[LDP] = ((kt - 1) & 1) ? pstB : pstA;
            const unsigned short (*vts)[LDP] = ((kt - 1) & 1) ? vtsB : vtsA;
            __builtin_amdgcn_s_setprio(1);
            #pragma unroll
            for (int s = 0; s < 4; s++) {
                bf16x8 av = *(const bf16x8*)&vts[kh * 32 + q31][s * 16 + hi * 8];
                bf16x8 bp = *(const bf16x8*)&pst[qrow][s * 16 + hi * 8];
                of  = __builtin_amdgcn_mfma_f32_32x32x16_bf16(av, bp, of, 0, 0, 0);
                ofl = __builtin_amdgcn_mfma_f32_32x32x16_bf16(ones, bp, ofl, 0, 0, 0);
            }
            __builtin_amdgcn_s_setprio(0);
        }

        // ---- St(kt): quadrant (kh, qh); A = K read once, B = Q in regs
        f32x16 sf;
        #pragma unroll
        for (int i = 0; i < 16; i++) sf[i] = -M2;
        __builtin_amdgcn_s_setprio(1);
        {
            bf16x8 ak = *(const bf16x8*)&ks[kh * 32 + q31][hi * 8];
            sf = __builtin_amdgcn_mfma_f32_32x32x16_bf16(ak, bq0, sf, 0, 0, 0);
            ak = *(const bf16x8*)&ks[kh * 32 + q31][16 + hi * 8];
            sf = __builtin_amdgcn_mfma_f32_32x32x16_bf16(ak, bq1, sf, 0, 0, 0);
            ak = *(const bf16x8*)&ks[kh * 32 + q31][32 + hi * 8];
            sf = __builtin_amdgcn_mfma_f32_32x32x16_bf16(ak, bq2, sf, 0, 0, 0);
            ak = *(const bf16x8*)&ks[kh * 32 + q31][48 + hi * 8];
            sf = __builtin_amdgcn_mfma_f32_32x32x16_bf16(ak, bq3, sf, 0, 0, 0);
        }
        __builtin_amdgcn_s_setprio(0);

        // ---- softmax numerator -> packed pdw (D row = (r&3)+8*(r>>2)+4*hi)
        const bool diag = (kt == qt);
        #pragma unroll
        for (int g = 0; g < 4; g++) {
            float p[4];
            #pragma unroll
            for (int r2 = 0; r2 < 4; r2++) {
                float pv = fast_exp2(sf[g * 4 + r2]);
                if (diag) {
                    const int kl = kh * 32 + 8 * g + 4 * hi + r2;
                    if (kl > qrow) pv = 0.f;
                }
                p[r2] = pv;
            }
            pdw[g * 2]     = packhi(p[0], p[1]);
            pdw[g * 2 + 1] = packhi(p[2], p[3]);
        }
    }

    // ---- tail: publish P(k1-1), then final PV
    {
        unsigned short (*pst)[LDP] = ((k1 - 1) & 1) ? pstB : pstA;
        const int cb = kh * 32 + 4 * hi;
        *(uint2*)&pst[qrow][cb +  0] = *(uint2*)&pdw[0];
        *(uint2*)&pst[qrow][cb +  8] = *(uint2*)&pdw[2];
        *(uint2*)&pst[qrow][cb + 16] = *(uint2*)&pdw[4];
        *(uint2*)&pst[qrow][cb + 24] = *(uint2*)&pdw[6];
        __syncthreads();
        const unsigned short (*pstc)[LDP] = ((k1 - 1) & 1) ? pstB : pstA;
        const unsigned short (*vts)[LDP]  = ((k1 - 1) & 1) ? vtsB : vtsA;
        __builtin_amdgcn_s_setprio(1);
        #pragma unroll
        for (int s = 0; s < 4; s++) {
            bf16x8 av = *(const bf16x8*)&vts[kh * 32 + q31][s * 16 + hi * 8];
            bf16x8 bp = *(const bf16x8*)&pstc[qrow][s * 16 + hi * 8];
            of  = __builtin_amdgcn_mfma_f32_32x32x16_bf16(av, bp, of, 0, 0, 0);
            ofl = __builtin_amdgcn_mfma_f32_32x32x16_bf16(ones, bp, ofl, 0, 0, 0);
        }
        __builtin_amdgcn_s_setprio(0);
    }

    // ---- write out: lane holds O[d = kh*32 + (r&3)+8*(r>>2)+4*hi][q = qrow]
    const float l = ofl[0];   // all-ones A => every acc reg = l[q]
    if (whole) {
        const float inv = 1.f / l;
        float* op = O + ((size_t)bh * S_LEN + qt * 64 + qrow) * DHDIM
                  + kh * 32 + 4 * hi;
        #pragma unroll
        for (int g = 0; g < 4; g++)
            *(float4*)(op + 8 * g) = make_float4(
                of[4 * g] * inv, of[4 * g + 1] * inv,
                of[4 * g + 2] * inv, of[4 * g + 3] * inv);
    } else {
        const int slot = bh * NSLOT + sl;
        if (kh == 0 && hi == 0) pL[slot * 64 + qrow] = l;
        float* op = pO + (size_t)slot * 4096 + qrow * 64 + kh * 32 + 4 * hi;
        #pragma unroll
        for (int g = 0; g < 4; g++)
            *(float4*)(op + 8 * g) = make_float4(
                of[4 * g], of[4 * g + 1], of[4 * g + 2], of[4 * g + 3]);
    }
}

// ---- combine: O = sum(Oi) / sum(li), per (bh, qt) for qt in [11,31]
__global__ __launch_bounds__(256) void combine(
    const float* __restrict__ pO, const float* __restrict__ pL,
    float* __restrict__ O)
{
    const int qt = 11 + blockIdx.x, bh = blockIdx.y;
    int base, cnt;
    if (qt < 22) { base = (qt - 11) * 2;      cnt = 2; }
    else         { base = 22 + 3 * (qt - 22); cnt = 3; }
    const int sb = bh * NSLOT + base;
    const float* A = pO + (size_t)sb * 4096;
    float* out = O + ((size_t)bh * S_LEN + qt * 64) * DHDIM;
    #pragma unroll
    for (int k = 0; k < 4; k++) {
        int c = threadIdx.x + k * 256;     // float4 chunk 0..1023
        int row = c >> 4;
        float l = pL[sb * 64 + row] + pL[(sb + 1) * 64 + row];
        float4 a = *(const float4*)(A + c * 4);
        float4 b = *(const float4*)(A + 4096 + c * 4);
        float4 s = make_float4(a.x + b.x, a.y + b.y, a.z + b.z, a.w + b.w);
        if (cnt == 3) {
            l += pL[(sb + 2) * 64 + row];
            float4 d = *(const float4*)(A + 8192 + c * 4);
            s = make_float4(s.x + d.x, s.y + d.y, s.z + d.z, s.w + d.w);
        }
        float inv = 1.f / l;
        *(float4*)(out + c * 4) = make_float4(
            s.x * inv, s.y * inv, s.z * inv, s.w * inv);
    }
}

// ---- fallback kernels (whole-row blocks), used when ws too small
template <bool PRE>
__global__ __launch_bounds__(256) void fattn_kernel(
    const void* __restrict__ Qp, const void* __restrict__ Kp,
    const void* __restrict__ Vp, float* __restrict__ O)
{
    __shared__ unsigned short smem[192 * LDP];
    unsigned short (*ks)[LDP]  = (unsigned short(*)[LDP])smem;
    unsigned short (*vts)[LDP] = (unsigned short(*)[LDP])(smem + 64 * LDP);
    unsigned short (*qs)[LDP]  = (unsigned short(*)[LDP])(smem + 128 * LDP);
    unsigned short (*pst)[LDP] = qs;

    const int id = blockIdx.y * 32 + blockIdx.x;
    const int g  = id >> 8;
    const int r8 = id & 255;
    const int bh = r8 >> 3;
    const int s8 = r8 & 7;
    const int qt = (g == 0) ? 31 - 2 * s8 : (g == 1) ? 2 * s8
                 : (g == 2) ? 30 - 2 * s8 : 2 * s8 + 1;

    const int tid = threadIdx.x;
    const int wave = tid >> 6, lane = tid & 63;
    const int quad = lane >> 4, l16 = lane & 15;

    if constexpr (PRE) {
        const unsigned short* src = (const unsigned short*)Qp
            + ((size_t)bh * S_LEN + qt * 64) * DHDIM;
        for (int c = tid; c < 512; c += 256) {
            int row = c >> 3, c8 = (c & 7) * 8;
            *(uint4*)&qs[row][c8] = *(const uint4*)(src + row * DHDIM + c8);
        }
    } else {
        const float* src = (const float*)Qp + ((size_t)bh * S_LEN + qt * 64) * DHDIM;
        for (int c = tid; c < 512; c += 256) {
            int row = c >> 3, c8 = (c & 7) * 8;
            float f[8]; ld8(src + row * DHDIM + c8, f);
            *(uint4*)&qs[row][c8] = pack8(f, QSCALE);
        }
    }
    __syncthreads();

    const int prow = wave * 16 + l16;
    const bf16x8 bq0 = *(const bf16x8*)&qs[prow][quad * 8];
    const bf16x8 bq1 = *(const bf16x8*)&qs[prow][32 + quad * 8];

    float l_p = 0.f;
    f32x4 of[4];
    #pragma unroll
    for (int n = 0; n < 4; n++) of[n] = (f32x4){0.f, 0.f, 0.f, 0.f};

    for (int kt = 0; kt <= qt; kt++) {
        __syncthreads();
        if constexpr (PRE) {
            const unsigned short* ksrc = (const unsigned short*)Kp
                + ((size_t)bh * S_LEN + kt * 64) * DHDIM;
            const unsigned short* vsrc = (const unsigned short*)Vp
                + (size_t)bh * DHDIM * S_LEN + kt * 64;
            for (int c = tid; c < 512; c += 256) {
                int row = c >> 3, c8 = (c & 7) * 8;
                *(uint4*)&ks[row][c8]  = *(const uint4*)(ksrc + row * DHDIM + c8);
                *(uint4*)&vts[row][c8] = *(const uint4*)(vsrc + (size_t)row * S_LEN + c8);
            }
        } else {
            const float* ksrc = (const float*)Kp + ((size_t)bh * S_LEN + kt * 64) * DHDIM;
            const float* vsrc = (const float*)Vp + ((size_t)bh * S_LEN + kt * 64) * DHDIM;
            for (int c = tid; c < 512; c += 256) {
                int row = c >> 3, c8 = (c & 7) * 8;
                float f[8];
                ld8(ksrc + row * DHDIM + c8, f);
                *(uint4*)&ks[row][c8] = pack8(f, 1.0f);
                ld8(vsrc + row * DHDIM + c8, f);
                #pragma unroll
                for (int j = 0; j < 8; j++) vts[c8 + j][row] = f2bf(f[j]);
            }
        }
        __syncthreads();

        f32x4 sf[4];
        #pragma unroll
        for (int n = 0; n < 4; n++) {
            bf16x8 ak0 = *(const bf16x8*)&ks[n * 16 + l16][quad * 8];
            bf16x8 ak1 = *(const bf16x8*)&ks[n * 16 + l16][32 + quad * 8];
            sf[n] = (f32x4){-M2, -M2, -M2, -M2};
            sf[n] = __builtin_amdgcn_mfma_f32_16x16x32_bf16(ak0, bq0, sf[n], 0, 0, 0);
            sf[n] = __builtin_amdgcn_mfma_f32_16x16x32_bf16(ak1, bq1, sf[n], 0, 0, 0);
        }

        const bool diag = (kt == qt);
        #pragma unroll
        for (int n = 0; n < 4; n++) {
            float p[4];
            #pragma unroll
            for (int r = 0; r < 4; r++) {
                p[r] = fast_exp2(sf[n][r]);
                if (diag && (n * 16 + quad * 4 + r > prow)) p[r] = 0.f;
                l_p += p[r];
            }
            uint2 dw;
            dw.x = packhi(p[0], p[1]);
            dw.y = packhi(p[2], p[3]);
            *(uint2*)&pst[prow][n * 16 + quad * 4] = dw;
        }
        asm volatile("s_waitcnt lgkmcnt(0)" ::: "memory");

        bf16x8 bp0 = *(const bf16x8*)&pst[prow][quad * 8];
        bf16x8 bp1 = *(const bf16x8*)&pst[prow][32 + quad * 8];
        #pragma unroll
        for (int n = 0; n < 4; n++) {
            bf16x8 av0 = *(const bf16x8*)&vts[n * 16 + l16][quad * 8];
            bf16x8 av1 = *(const bf16x8*)&vts[n * 16 + l16][32 + quad * 8];
            of[n] = __builtin_amdgcn_mfma_f32_16x16x32_bf16(av0, bp0, of[n], 0, 0, 0);
            of[n] = __builtin_amdgcn_mfma_f32_16x16x32_bf16(av1, bp1, of[n], 0, 0, 0);
        }
    }

    l_p += __shfl_xor(l_p, 16);
    l_p += __shfl_xor(l_p, 32);
    const float inv = 1.f / l_p;
    float* op = O + ((size_t)bh * S_LEN + qt * 64 + prow) * DHDIM;
    #pragma unroll
    for (int n = 0; n < 4; n++)
        *(float4*)(op + n * 16 + quad * 4) = make_float4(
            of[n][0] * inv, of[n][1] * inv, of[n][2] * inv, of[n][3] * inv);
}

extern "C" void kernel_launch(void* const* d_in, const int* in_sizes, int n_in,
                              void* d_out, int out_size, void* d_ws, size_t ws_size,
                              hipStream_t stream) {
    const float* Q = (const float*)d_in[0];
    const float* K = (const float*)d_in[1];
    const float* V = (const float*)d_in[2];
    // d_in[3] = causal mask: analytic, not read.
    float* O = (float*)d_out;
    const size_t N = (size_t)NHEADS * S_LEN * DHDIM;      // 4,194,304 elems
    const size_t prepB  = 3 * N * sizeof(unsigned short); // 25.2 MB
    // 52 partial slots per bh (qt>=11 pieces): O-partials + l
    const size_t partB  = (size_t)NSLOT * 32 * (4096 + 64) * sizeof(float); // 27.7 MB

    if (d_ws && ws_size >= prepB + partB) {
        unsigned short* qb  = (unsigned short*)d_ws;
        unsigned short* kb  = qb + N;
        unsigned short* vtb = kb + N;
        float* pO = (float*)((char*)d_ws + prepB);
        float* pL = pO + (size_t)NSLOT * 32 * 4096;
        prep<<<dim3(S_LEN / 64, NHEADS), 256, 0, stream>>>(Q, K, V, qb, kb, vtb);
        fattn_splitk<<<dim3(32, 63), 256, 0, stream>>>(qb, kb, vtb, pO, pL, O);
        combine<<<dim3(21, 32), 256, 0, stream>>>(pO, pL, O);
    } else if (d_ws && ws_size >= prepB) {
        unsigned short* qb  = (unsigned short*)d_ws;
        unsigned short* kb  = qb + N;
        unsigned short* vtb = kb + N;
        prep<<<dim3(S_LEN / 64, NHEADS), 256, 0, stream>>>(Q, K, V, qb, kb, vtb);
        fattn_kernel<true><<<dim3(32, 32), 256, 0, stream>>>(qb, kb, vtb, O);
    } else {
        fattn_kernel<false><<<dim3(32, 32), 256, 0, stream>>>(Q, K, V, O);
    }
}

// Round 10
// 139.693 us; speedup vs baseline: 1.1862x; 1.0144x over previous
//
#include <hip/hip_runtime.h>

// Causal MHA: B=2, H=16, S=2048, DH=64. fp32 in/out. bf16 MFMA inside.
// R19: in-register P via hi-half swap; pst + ones-MFMA eliminated.
// R18 verified the 32x32 layouts on HW and showed conflicts/LDS traffic were
// mostly hidden (-82% conflicts -> -1.3us). Remaining per-tile critical path:
// pst round-trip + 2nd barrier + ones-MFMA (1/3 of MFMA cycles). Key insight:
// 32x32 D-layout rows per lane ({4hi+r,8+4hi+r,..}) vs PV B-frag rows
// ({8hi+j}) differ only by a hi-half exchange -- lane (q,hi) owns exactly the
// dwords lane (q,hi^1) needs. Two __shfl_xor(.,32)+select per K=16 slice turn
// St's D-layout into PV's B-frag IN REGISTERS. pst gone; P never touches LDS.
// Each wave has P only for its own 32-k slice -> PV computed as per-kh
// partials over BOTH d-halves (of = 2 x f32x16), reduced once per item via an
// R13-style LDS epilogue (amortized over ~8.5 tiles). l = 16 VALU adds
// (ones-MFMA gone: MFMA/wave-tile 12->8). Barriers 1/tile (K+V double-buf,
// 36KB LDS, 4 blocks/CU). Scheduling/RTAB/prep/combine = R15/R18 verbatim.

#define S_LEN  2048
#define DHDIM  64
#define NHEADS 32   // B*H
#define LDP    72   // padded LDS row length in shorts (144B = 9*16B)
#define M2     23.083120654223414f   // 16 * log2(e)
#define QSCALE 0.18033688011117658f  // 0.125 * log2(e)
#define NSLOT  52   // partial slots per bh

typedef __attribute__((ext_vector_type(8))) short bf16x8;
typedef __attribute__((ext_vector_type(4))) float f32x4;
typedef __attribute__((ext_vector_type(16))) float f32x16;

// rank table: 63 items per bh, LPT (desc length) order.
// entry = qt<<24 | k0<<16 | k1<<8 | slot  (slot 255 = whole row, direct O)
#define RT(qt,k0,k1,sl) ((unsigned)(qt)<<24 | (unsigned)(k0)<<16 | (unsigned)(k1)<<8 | (unsigned)(sl))
__device__ __constant__ unsigned RTAB[63] = {
    RT(31,0,11,49),  RT(31,11,22,50), RT(30,0,11,46),  RT(21,0,11,20),
    RT(21,11,22,21), RT(20,0,11,18),  RT(10,0,11,255),
    RT(31,22,32,51), RT(30,11,21,47), RT(30,21,31,48), RT(29,0,10,43),
    RT(29,10,20,44), RT(29,20,30,45), RT(28,0,10,40),  RT(28,10,20,41),
    RT(27,0,10,37),  RT(20,11,21,19), RT(19,0,10,16),  RT(19,10,20,17),
    RT(18,0,10,14),  RT(9,0,10,255),
    RT(28,20,29,42), RT(27,10,19,38), RT(27,19,28,39), RT(26,0,9,34),
    RT(26,9,18,35),  RT(26,18,27,36), RT(25,0,9,31),   RT(25,9,18,32),
    RT(24,0,9,28),   RT(18,10,19,15), RT(17,0,9,12),   RT(17,9,18,13),
    RT(16,0,9,10),   RT(8,0,9,255),
    RT(25,18,26,33), RT(24,9,17,29),  RT(24,17,25,30), RT(23,0,8,25),
    RT(23,8,16,26),  RT(23,16,24,27), RT(22,0,8,22),   RT(22,8,16,23),
    RT(16,9,17,11),  RT(15,0,8,8),    RT(15,8,16,9),   RT(14,0,8,6),
    RT(7,0,8,255),
    RT(22,16,23,24), RT(14,8,15,7),   RT(13,0,7,4),    RT(13,7,14,5),
    RT(12,0,7,2),    RT(6,0,7,255),
    RT(12,7,13,3),   RT(11,0,6,0),    RT(11,6,12,1),   RT(5,0,6,255),
    RT(4,0,5,255),   RT(3,0,4,255),   RT(2,0,3,255),   RT(1,0,2,255),
    RT(0,0,1,255)};

__device__ __forceinline__ float fast_exp2(float x) {
#if __has_builtin(__builtin_amdgcn_exp2f)
    return __builtin_amdgcn_exp2f(x);
#else
    return exp2f(x);
#endif
}
__device__ __forceinline__ unsigned short f2bf(float f) { // RNE
    unsigned u = __float_as_uint(f);
    return (unsigned short)((u + 0x7fffu + ((u >> 16) & 1u)) >> 16);
}
__device__ __forceinline__ void ld8(const float* p, float* f) {
    float4 a = *(const float4*)p, b = *(const float4*)(p + 4);
    f[0]=a.x; f[1]=a.y; f[2]=a.z; f[3]=a.w; f[4]=b.x; f[5]=b.y; f[6]=b.z; f[7]=b.w;
}
__device__ __forceinline__ uint4 pack8(const float* f, float scale) {
    union { uint4 v; unsigned short s[8]; } w;
    #pragma unroll
    for (int j = 0; j < 8; j++) w.s[j] = f2bf(f[j] * scale);
    return w.v;
}
// combine high-16s of two floats into one dword: [lo16=a.hi16, hi16=b.hi16]
__device__ __forceinline__ unsigned packhi(float a, float b) {
#if __has_builtin(__builtin_amdgcn_perm)
    return __builtin_amdgcn_perm(__float_as_uint(b), __float_as_uint(a), 0x07060302u);
#else
    return (__float_as_uint(a) >> 16) | (__float_as_uint(b) & 0xffff0000u);
#endif
}
__device__ __forceinline__ bf16x8 mk_bf16x8(unsigned d0, unsigned d1,
                                            unsigned d2, unsigned d3) {
    union { unsigned u[4]; bf16x8 v; } w;
    w.u[0] = d0; w.u[1] = d1; w.u[2] = d2; w.u[3] = d3;
    return w.v;
}

// ---- pre-pass: per block (st, bh): V 64x64 tile -> bf16 V^T tile, plus a
// 4096-elem chunk of Q (scaled) and K -> bf16.
__global__ __launch_bounds__(256) void prep(
    const float* __restrict__ Qf, const float* __restrict__ Kf,
    const float* __restrict__ Vf, unsigned short* __restrict__ qb,
    unsigned short* __restrict__ kb, unsigned short* __restrict__ vtb)
{
    const int st = blockIdx.x, bh = blockIdx.y;
    __shared__ unsigned lt32[64][LDP / 2];   // dword view: 36 dwords/row
    const float* vp = Vf + ((size_t)bh * S_LEN + st * 64) * DHDIM;
    {
        const int c = threadIdx.x;
        const int sp = c >> 3;            // s-pair index 0..31
        const int d0 = (c & 7) * 8;
        float fa[8], fb[8];
        ld8(vp + (2 * sp) * DHDIM + d0, fa);
        ld8(vp + (2 * sp + 1) * DHDIM + d0, fb);
        #pragma unroll
        for (int j = 0; j < 8; j++) {
            int d = d0 + j;
            int colw = (sp & 3) | ((((sp >> 2) ^ (d >> 3)) & 7) << 2);
            lt32[d][colw] = (unsigned)f2bf(fa[j]) | ((unsigned)f2bf(fb[j]) << 16);
        }
    }
    size_t off = ((size_t)(bh * 32 + st) * 4096) + (size_t)threadIdx.x * 16;
    float f[8];
    ld8(Qf + off, f);     *(uint4*)(qb + off)     = pack8(f, QSCALE);
    ld8(Qf + off + 8, f); *(uint4*)(qb + off + 8) = pack8(f, QSCALE);
    ld8(Kf + off, f);     *(uint4*)(kb + off)     = pack8(f, 1.0f);
    ld8(Kf + off + 8, f); *(uint4*)(kb + off + 8) = pack8(f, 1.0f);
    __syncthreads();
    unsigned short* op = vtb + (size_t)bh * DHDIM * S_LEN + st * 64;
    for (int c = threadIdx.x; c < 512; c += 256) {
        int d = c >> 3, q = c & 7;
        int colw = ((q ^ (d >> 3)) & 7) << 2;
        *(uint4*)(op + (size_t)d * S_LEN + q * 8) = *(const uint4*)&lt32[d][colw];
    }
}

// ---- main: block = (bh, rank). 4 waves = (kh, qh). P never touches LDS.
__global__ __launch_bounds__(256) void fattn_splitk(
    const unsigned short* __restrict__ Qp, const unsigned short* __restrict__ Kp,
    const unsigned short* __restrict__ Vp,
    float* __restrict__ pO, float* __restrict__ pL, float* __restrict__ O)
{
    __shared__ unsigned short smem[256 * LDP]; // ksA | ksB | vtsA | vtsB (36.9KB)
    unsigned short (*ksA)[LDP]  = (unsigned short(*)[LDP])smem;
    unsigned short (*ksB)[LDP]  = (unsigned short(*)[LDP])(smem + 64 * LDP);
    unsigned short (*vtsA)[LDP] = (unsigned short(*)[LDP])(smem + 128 * LDP);
    unsigned short (*vtsB)[LDP] = (unsigned short(*)[LDP])(smem + 192 * LDP);

    const int bh   = blockIdx.x;           // 0..31
    const unsigned e = RTAB[blockIdx.y];   // 0..62, longest-first
    const int qt   = e >> 24;
    const int k0   = (e >> 16) & 255;
    const int k1   = (e >> 8) & 255;
    const int sl   = e & 255;
    const bool whole = (sl == 255);

    const int tid  = threadIdx.x;
    const int wave = tid >> 6, lane = tid & 63;
    const int q31  = lane & 31, hi = lane >> 5;
    const int qh   = wave & 1, kh = wave >> 1;
    const int qrow = qh * 32 + q31;              // local q row 0..63

    // ---- Q B-fragments, direct from global (pre-scaled bf16 from prep)
    const unsigned short* qsrc = Qp + ((size_t)bh * S_LEN + qt * 64 + qrow) * DHDIM;
    const bf16x8 bq0 = *(const bf16x8*)(qsrc + hi * 8);
    const bf16x8 bq1 = *(const bf16x8*)(qsrc + 16 + hi * 8);
    const bf16x8 bq2 = *(const bf16x8*)(qsrc + 32 + hi * 8);
    const bf16x8 bq3 = *(const bf16x8*)(qsrc + 48 + hi * 8);

    f32x16 of2[2];   // PV partials over own kh k-slice, both d-halves
    #pragma unroll
    for (int i = 0; i < 16; i++) { of2[0][i] = 0.f; of2[1][i] = 0.f; }
    float l_p = 0.f;

    // ---- staging + prefetch (R12 scheme), K+V double-buffered
    const unsigned short* Kbh = Kp + (size_t)bh * S_LEN * DHDIM;
    const unsigned short* Vbh = Vp + (size_t)bh * DHDIM * S_LEN;
    const int sr = tid >> 3, sc = (tid & 7) * 8;
    uint4 kr0, kr1, vr0, vr1;
    {
        const unsigned short* ksrc = Kbh + (size_t)k0 * 64 * DHDIM;
        const unsigned short* vsrc = Vbh + k0 * 64;
        kr0 = *(const uint4*)(ksrc + sr * DHDIM + sc);
        kr1 = *(const uint4*)(ksrc + (sr + 32) * DHDIM + sc);
        vr0 = *(const uint4*)(vsrc + (size_t)sr * S_LEN + sc);
        vr1 = *(const uint4*)(vsrc + (size_t)(sr + 32) * S_LEN + sc);
    }
    {   // prologue: write tile k0 into its buffer
        unsigned short (*ks)[LDP]  = (k0 & 1) ? ksB : ksA;
        unsigned short (*vts)[LDP] = (k0 & 1) ? vtsB : vtsA;
        *(uint4*)&ks[sr][sc]       = kr0;
        *(uint4*)&ks[sr + 32][sc]  = kr1;
        *(uint4*)&vts[sr][sc]      = vr0;
        *(uint4*)&vts[sr + 32][sc] = vr1;
    }
    if (k0 + 1 < k1) {
        const unsigned short* ksrc = Kbh + (size_t)(k0 + 1) * 64 * DHDIM;
        const unsigned short* vsrc = Vbh + (k0 + 1) * 64;
        kr0 = *(const uint4*)(ksrc + sr * DHDIM + sc);
        kr1 = *(const uint4*)(ksrc + (sr + 32) * DHDIM + sc);
        vr0 = *(const uint4*)(vsrc + (size_t)sr * S_LEN + sc);
        vr1 = *(const uint4*)(vsrc + (size_t)(sr + 32) * S_LEN + sc);
    }

    for (int kt = k0; kt < k1; kt++) {
        __syncthreads();  // buf[kt&1] written; prior reads of buf[(kt+1)&1] done

        if (kt + 1 < k1) {  // write next tile's buffer; prefetch kt+2
            unsigned short (*ks)[LDP]  = ((kt + 1) & 1) ? ksB : ksA;
            unsigned short (*vts)[LDP] = ((kt + 1) & 1) ? vtsB : vtsA;
            *(uint4*)&ks[sr][sc]       = kr0;
            *(uint4*)&ks[sr + 32][sc]  = kr1;
            *(uint4*)&vts[sr][sc]      = vr0;
            *(uint4*)&vts[sr + 32][sc] = vr1;
            if (kt + 2 < k1) {
                const unsigned short* ksrc = Kbh + (size_t)(kt + 2) * 64 * DHDIM;
                const unsigned short* vsrc = Vbh + (kt + 2) * 64;
                kr0 = *(const uint4*)(ksrc + sr * DHDIM + sc);
                kr1 = *(const uint4*)(ksrc + (sr + 32) * DHDIM + sc);
                vr0 = *(const uint4*)(vsrc + (size_t)sr * S_LEN + sc);
                vr1 = *(const uint4*)(vsrc + (size_t)(sr + 32) * S_LEN + sc);
            }
        }

        const unsigned short (*ksc)[LDP] = (kt & 1) ? ksB : ksA;
        const unsigned short (*vtc)[LDP] = (kt & 1) ? vtsB : vtsA;

        // ---- St(kt): quadrant (kh, qh); A = K read once, B = Q in regs
        f32x16 sf;
        #pragma unroll
        for (int i = 0; i < 16; i++) sf[i] = -M2;
        __builtin_amdgcn_s_setprio(1);
        {
            bf16x8 ak = *(const bf16x8*)&ksc[kh * 32 + q31][hi * 8];
            sf = __builtin_amdgcn_mfma_f32_32x32x16_bf16(ak, bq0, sf, 0, 0, 0);
            ak = *(const bf16x8*)&ksc[kh * 32 + q31][16 + hi * 8];
            sf = __builtin_amdgcn_mfma_f32_32x32x16_bf16(ak, bq1, sf, 0, 0, 0);
            ak = *(const bf16x8*)&ksc[kh * 32 + q31][32 + hi * 8];
            sf = __builtin_amdgcn_mfma_f32_32x32x16_bf16(ak, bq2, sf, 0, 0, 0);
            ak = *(const bf16x8*)&ksc[kh * 32 + q31][48 + hi * 8];
            sf = __builtin_amdgcn_mfma_f32_32x32x16_bf16(ak, bq3, sf, 0, 0, 0);
        }
        __builtin_amdgcn_s_setprio(0);

        // ---- softmax numerator -> packed pdw; l accumulates in VALU
        const bool diag = (kt == qt);
        unsigned pdw[8];
        #pragma unroll
        for (int g = 0; g < 4; g++) {
            float p[4];
            #pragma unroll
            for (int r2 = 0; r2 < 4; r2++) {
                float pv = fast_exp2(sf[g * 4 + r2]);
                if (diag) {
                    const int kl = kh * 32 + 8 * g + 4 * hi + r2;
                    if (kl > qrow) pv = 0.f;
                }
                p[r2] = pv;
                l_p += pv;
            }
            pdw[g * 2]     = packhi(p[0], p[1]);
            pdw[g * 2 + 1] = packhi(p[2], p[3]);
        }

        // ---- PV(kt) in-register: hi-half swap turns D-layout into B-frag.
        // slice js (k = 16js..16js+15 within quadrant, global s = 2kh+js):
        //   j01 = hi? partner(pdw[4js+2]) : pdw[4js]
        //   j23 = hi? partner(pdw[4js+3]) : pdw[4js+1]
        //   j45 = hi? pdw[4js+2] : partner(pdw[4js])
        //   j67 = hi? pdw[4js+3] : partner(pdw[4js+1])
        __builtin_amdgcn_s_setprio(1);
        #pragma unroll
        for (int js = 0; js < 2; js++) {
            const unsigned a0 = pdw[4 * js],     a1 = pdw[4 * js + 1];
            const unsigned b0 = pdw[4 * js + 2], b1 = pdw[4 * js + 3];
            const unsigned pa0 = __shfl_xor(a0, 32), pa1 = __shfl_xor(a1, 32);
            const unsigned pb0 = __shfl_xor(b0, 32), pb1 = __shfl_xor(b1, 32);
            const bf16x8 bp = mk_bf16x8(hi ? pb0 : a0, hi ? pb1 : a1,
                                        hi ? b0 : pa0, hi ? b1 : pa1);
            const int scol = (2 * kh + js) * 16 + hi * 8;
            bf16x8 av = *(const bf16x8*)&vtc[q31][scol];
            of2[0] = __builtin_amdgcn_mfma_f32_32x32x16_bf16(av, bp, of2[0], 0, 0, 0);
            av = *(const bf16x8*)&vtc[32 + q31][scol];
            of2[1] = __builtin_amdgcn_mfma_f32_32x32x16_bf16(av, bp, of2[1], 0, 0, 0);
        }
        __builtin_amdgcn_s_setprio(0);
    }

    // ---- epilogue: l across hi, then cross-kh reduction of O + l via LDS
    float l2 = l_p + __shfl_xor(l_p, 32);
    __syncthreads();                  // all tiles done; smem reusable
    float* fs = (float*)smem;
    const int base = (qh * 64 + lane) * 36;   // 36 floats stride: 16B-aligned
    if (kh == 1) {
        #pragma unroll
        for (int dh = 0; dh < 2; dh++)
            #pragma unroll
            for (int g = 0; g < 4; g++)
                *(float4*)&fs[base + dh * 16 + g * 4] = make_float4(
                    of2[dh][4 * g], of2[dh][4 * g + 1],
                    of2[dh][4 * g + 2], of2[dh][4 * g + 3]);
        fs[base + 32] = l2;
    }
    __syncthreads();
    if (kh == 0) {
        #pragma unroll
        for (int dh = 0; dh < 2; dh++)
            #pragma unroll
            for (int g = 0; g < 4; g++) {
                float4 a = *(const float4*)&fs[base + dh * 16 + g * 4];
                of2[dh][4 * g]     += a.x;
                of2[dh][4 * g + 1] += a.y;
                of2[dh][4 * g + 2] += a.z;
                of2[dh][4 * g + 3] += a.w;
            }
        l2 += fs[base + 32];

        // lane holds O[d = dh*32 + 8g + 4hi + r][q = qrow], full K-range
        if (whole) {
            const float inv = 1.f / l2;
            float* op = O + ((size_t)bh * S_LEN + qt * 64 + qrow) * DHDIM;
            #pragma unroll
            for (int dh = 0; dh < 2; dh++)
                #pragma unroll
                for (int g = 0; g < 4; g++)
                    *(float4*)(op + dh * 32 + 8 * g + 4 * hi) = make_float4(
                        of2[dh][4 * g] * inv, of2[dh][4 * g + 1] * inv,
                        of2[dh][4 * g + 2] * inv, of2[dh][4 * g + 3] * inv);
        } else {
            const int slot = bh * NSLOT + sl;
            if (hi == 0) pL[slot * 64 + qrow] = l2;
            float* op = pO + (size_t)slot * 4096 + qrow * 64;
            #pragma unroll
            for (int dh = 0; dh < 2; dh++)
                #pragma unroll
                for (int g = 0; g < 4; g++)
                    *(float4*)(op + dh * 32 + 8 * g + 4 * hi) = make_float4(
                        of2[dh][4 * g], of2[dh][4 * g + 1],
                        of2[dh][4 * g + 2], of2[dh][4 * g + 3]);
        }
    }
}

// ---- combine: O = sum(Oi) / sum(li), per (bh, qt) for qt in [11,31]
__global__ __launch_bounds__(256) void combine(
    const float* __restrict__ pO, const float* __restrict__ pL,
    float* __restrict__ O)
{
    const int qt = 11 + blockIdx.x, bh = blockIdx.y;
    int base, cnt;
    if (qt < 22) { base = (qt - 11) * 2;      cnt = 2; }
    else         { base = 22 + 3 * (qt - 22); cnt = 3; }
    const int sb = bh * NSLOT + base;
    const float* A = pO + (size_t)sb * 4096;
    float* out = O + ((size_t)bh * S_LEN + qt * 64) * DHDIM;
    #pragma unroll
    for (int k = 0; k < 4; k++) {
        int c = threadIdx.x + k * 256;     // float4 chunk 0..1023
        int row = c >> 4;
        float l = pL[sb * 64 + row] + pL[(sb + 1) * 64 + row];
        float4 a = *(const float4*)(A + c * 4);
        float4 b = *(const float4*)(A + 4096 + c * 4);
        float4 s = make_float4(a.x + b.x, a.y + b.y, a.z + b.z, a.w + b.w);
        if (cnt == 3) {
            l += pL[(sb + 2) * 64 + row];
            float4 d = *(const float4*)(A + 8192 + c * 4);
            s = make_float4(s.x + d.x, s.y + d.y, s.z + d.z, s.w + d.w);
        }
        float inv = 1.f / l;
        *(float4*)(out + c * 4) = make_float4(
            s.x * inv, s.y * inv, s.z * inv, s.w * inv);
    }
}

// ---- fallback kernels (whole-row blocks), used when ws too small
template <bool PRE>
__global__ __launch_bounds__(256) void fattn_kernel(
    const void* __restrict__ Qp, const void* __restrict__ Kp,
    const void* __restrict__ Vp, float* __restrict__ O)
{
    __shared__ unsigned short smem[192 * LDP];
    unsigned short (*ks)[LDP]  = (unsigned short(*)[LDP])smem;
    unsigned short (*vts)[LDP] = (unsigned short(*)[LDP])(smem + 64 * LDP);
    unsigned short (*qs)[LDP]  = (unsigned short(*)[LDP])(smem + 128 * LDP);
    unsigned short (*pst)[LDP] = qs;

    const int id = blockIdx.y * 32 + blockIdx.x;
    const int g  = id >> 8;
    const int r8 = id & 255;
    const int bh = r8 >> 3;
    const int s8 = r8 & 7;
    const int qt = (g == 0) ? 31 - 2 * s8 : (g == 1) ? 2 * s8
                 : (g == 2) ? 30 - 2 * s8 : 2 * s8 + 1;

    const int tid = threadIdx.x;
    const int wave = tid >> 6, lane = tid & 63;
    const int quad = lane >> 4, l16 = lane & 15;

    if constexpr (PRE) {
        const unsigned short* src = (const unsigned short*)Qp
            + ((size_t)bh * S_LEN + qt * 64) * DHDIM;
        for (int c = tid; c < 512; c += 256) {
            int row = c >> 3, c8 = (c & 7) * 8;
            *(uint4*)&qs[row][c8] = *(const uint4*)(src + row * DHDIM + c8);
        }
    } else {
        const float* src = (const float*)Qp + ((size_t)bh * S_LEN + qt * 64) * DHDIM;
        for (int c = tid; c < 512; c += 256) {
            int row = c >> 3, c8 = (c & 7) * 8;
            float f[8]; ld8(src + row * DHDIM + c8, f);
            *(uint4*)&qs[row][c8] = pack8(f, QSCALE);
        }
    }
    __syncthreads();

    const int prow = wave * 16 + l16;
    const bf16x8 bq0 = *(const bf16x8*)&qs[prow][quad * 8];
    const bf16x8 bq1 = *(const bf16x8*)&qs[prow][32 + quad * 8];

    float l_p = 0.f;
    f32x4 of[4];
    #pragma unroll
    for (int n = 0; n < 4; n++) of[n] = (f32x4){0.f, 0.f, 0.f, 0.f};

    for (int kt = 0; kt <= qt; kt++) {
        __syncthreads();
        if constexpr (PRE) {
            const unsigned short* ksrc = (const unsigned short*)Kp
                + ((size_t)bh * S_LEN + kt * 64) * DHDIM;
            const unsigned short* vsrc = (const unsigned short*)Vp
                + (size_t)bh * DHDIM * S_LEN + kt * 64;
            for (int c = tid; c < 512; c += 256) {
                int row = c >> 3, c8 = (c & 7) * 8;
                *(uint4*)&ks[row][c8]  = *(const uint4*)(ksrc + row * DHDIM + c8);
                *(uint4*)&vts[row][c8] = *(const uint4*)(vsrc + (size_t)row * S_LEN + c8);
            }
        } else {
            const float* ksrc = (const float*)Kp + ((size_t)bh * S_LEN + kt * 64) * DHDIM;
            const float* vsrc = (const float*)Vp + ((size_t)bh * S_LEN + kt * 64) * DHDIM;
            for (int c = tid; c < 512; c += 256) {
                int row = c >> 3, c8 = (c & 7) * 8;
                float f[8];
                ld8(ksrc + row * DHDIM + c8, f);
                *(uint4*)&ks[row][c8] = pack8(f, 1.0f);
                ld8(vsrc + row * DHDIM + c8, f);
                #pragma unroll
                for (int j = 0; j < 8; j++) vts[c8 + j][row] = f2bf(f[j]);
            }
        }
        __syncthreads();

        f32x4 sf[4];
        #pragma unroll
        for (int n = 0; n < 4; n++) {
            bf16x8 ak0 = *(const bf16x8*)&ks[n * 16 + l16][quad * 8];
            bf16x8 ak1 = *(const bf16x8*)&ks[n * 16 + l16][32 + quad * 8];
            sf[n] = (f32x4){-M2, -M2, -M2, -M2};
            sf[n] = __builtin_amdgcn_mfma_f32_16x16x32_bf16(ak0, bq0, sf[n], 0, 0, 0);
            sf[n] = __builtin_amdgcn_mfma_f32_16x16x32_bf16(ak1, bq1, sf[n], 0, 0, 0);
        }

        const bool diag = (kt == qt);
        #pragma unroll
        for (int n = 0; n < 4; n++) {
            float p[4];
            #pragma unroll
            for (int r = 0; r < 4; r++) {
                p[r] = fast_exp2(sf[n][r]);
                if (diag && (n * 16 + quad * 4 + r > prow)) p[r] = 0.f;
                l_p += p[r];
            }
            uint2 dw;
            dw.x = packhi(p[0], p[1]);
            dw.y = packhi(p[2], p[3]);
            *(uint2*)&pst[prow][n * 16 + quad * 4] = dw;
        }
        asm volatile("s_waitcnt lgkmcnt(0)" ::: "memory");

        bf16x8 bp0 = *(const bf16x8*)&pst[prow][quad * 8];
        bf16x8 bp1 = *(const bf16x8*)&pst[prow][32 + quad * 8];
        #pragma unroll
        for (int n = 0; n < 4; n++) {
            bf16x8 av0 = *(const bf16x8*)&vts[n * 16 + l16][quad * 8];
            bf16x8 av1 = *(const bf16x8*)&vts[n * 16 + l16][32 + quad * 8];
            of[n] = __builtin_amdgcn_mfma_f32_16x16x32_bf16(av0, bp0, of[n], 0, 0, 0);
            of[n] = __builtin_amdgcn_mfma_f32_16x16x32_bf16(av1, bp1, of[n], 0, 0, 0);
        }
    }

    l_p += __shfl_xor(l_p, 16);
    l_p += __shfl_xor(l_p, 32);
    const float inv = 1.f / l_p;
    float* op = O + ((size_t)bh * S_LEN + qt * 64 + prow) * DHDIM;
    #pragma unroll
    for (int n = 0; n < 4; n++)
        *(float4*)(op + n * 16 + quad * 4) = make_float4(
            of[n][0] * inv, of[n][1] * inv, of[n][2] * inv, of[n][3] * inv);
}

extern "C" void kernel_launch(void* const* d_in, const int* in_sizes, int n_in,
                              void* d_out, int out_size, void* d_ws, size_t ws_size,
                              hipStream_t stream) {
    const float* Q = (const float*)d_in[0];
    const float* K = (const float*)d_in[1];
    const float* V = (const float*)d_in[2];
    // d_in[3] = causal mask: analytic, not read.
    float* O = (float*)d_out;
    const size_t N = (size_t)NHEADS * S_LEN * DHDIM;      // 4,194,304 elems
    const size_t prepB  = 3 * N * sizeof(unsigned short); // 25.2 MB
    // 52 partial slots per bh (qt>=11 pieces): O-partials + l
    const size_t partB  = (size_t)NSLOT * 32 * (4096 + 64) * sizeof(float); // 27.7 MB

    if (d_ws && ws_size >= prepB + partB) {
        unsigned short* qb  = (unsigned short*)d_ws;
        unsigned short* kb  = qb + N;
        unsigned short* vtb = kb + N;
        float* pO = (float*)((char*)d_ws + prepB);
        float* pL = pO + (size_t)NSLOT * 32 * 4096;
        prep<<<dim3(S_LEN / 64, NHEADS), 256, 0, stream>>>(Q, K, V, qb, kb, vtb);
        fattn_splitk<<<dim3(32, 63), 256, 0, stream>>>(qb, kb, vtb, pO, pL, O);
        combine<<<dim3(21, 32), 256, 0, stream>>>(pO, pL, O);
    } else if (d_ws && ws_size >= prepB) {
        unsigned short* qb  = (unsigned short*)d_ws;
        unsigned short* kb  = qb + N;
        unsigned short* vtb = kb + N;
        prep<<<dim3(S_LEN / 64, NHEADS), 256, 0, stream>>>(Q, K, V, qb, kb, vtb);
        fattn_kernel<true><<<dim3(32, 32), 256, 0, stream>>>(qb, kb, vtb, O);
    } else {
        fattn_kernel<false><<<dim3(32, 32), 256, 0, stream>>>(Q, K, V, O);
    }
}

// Round 11
// 139.023 us; speedup vs baseline: 1.1919x; 1.0048x over previous
//
#include <hip/hip_runtime.h>

// Causal MHA: B=2, H=16, S=2048, DH=64. fp32 in/out. bf16 MFMA inside.
// R20: 128-row q-tiles (q-pair items) on the R19 core. R19 proved the
// in-register-P 32x32 scheme; remaining cost = per-tile EVENTS (staging +
// barrier + latency), which the ledger shows is the stubborn ~40us floor.
// This round halves events per MFMA-work: 512 threads, 8 waves =
// (kh 0..1, qh 0..3); one K/V staging serves 128 q-rows. Staging events/bh
// 528 -> 272 (-48%), barriers likewise, Q-frag reloads halve. Per-wave
// state identical to R19 (of2[2], quadrant St, hi-half-swap PV, VALU l).
// Causal: diag_kt = gq>>6 is wave-uniform; waves skip kt > diag_kt
// (R19 computed those fully-masked tiles -- pure win). New 32-item/bh LPT
// table (pieces <= 11 tiles, 27 partial slots/bh, 128-row partials);
// combine sums 2-3 partials per q-pair. prep/fallbacks unchanged.

#define S_LEN  2048
#define DHDIM  64
#define NHEADS 32   // B*H
#define LDP    72   // padded LDS row length in shorts (144B = 9*16B)
#define M2     23.083120654223414f   // 16 * log2(e)
#define QSCALE 0.18033688011117658f  // 0.125 * log2(e)
#define NSLOT  27   // partial slots per bh (128-row slots)

typedef __attribute__((ext_vector_type(8))) short bf16x8;
typedef __attribute__((ext_vector_type(4))) float f32x4;
typedef __attribute__((ext_vector_type(16))) float f32x16;

// rank table: 32 items per bh (q-pairs qp=0..15), LPT (desc length) order.
// entry = qp<<24 | k0<<16 | k1<<8 | slot  (slot 255 = whole item, direct O)
#define RT(qp,k0,k1,sl) ((unsigned)(qp)<<24 | (unsigned)(k0)<<16 | (unsigned)(k1)<<8 | (unsigned)(sl))
__device__ __constant__ unsigned RTAB32[32] = {
    RT(15,0,11,24),  RT(15,11,22,25), RT(10,0,11,10),  RT(10,11,22,11),
    RT(15,22,32,26), RT(14,0,10,21),  RT(14,10,20,22), RT(14,20,30,23),
    RT(13,0,10,18),  RT(9,0,10,8),    RT(9,10,20,9),   RT(4,0,10,255),
    RT(13,10,19,19), RT(13,19,28,20), RT(12,0,9,15),   RT(12,9,18,16),
    RT(8,0,9,6),     RT(8,9,18,7),    RT(12,18,26,17), RT(11,0,8,12),
    RT(11,8,16,13),  RT(11,16,24,14), RT(7,0,8,4),     RT(7,8,16,5),
    RT(3,0,8,255),   RT(6,0,7,2),     RT(6,7,14,3),    RT(5,0,6,0),
    RT(5,6,12,1),    RT(2,0,6,255),   RT(1,0,4,255),   RT(0,0,2,255)};

__device__ __forceinline__ float fast_exp2(float x) {
#if __has_builtin(__builtin_amdgcn_exp2f)
    return __builtin_amdgcn_exp2f(x);
#else
    return exp2f(x);
#endif
}
__device__ __forceinline__ unsigned short f2bf(float f) { // RNE
    unsigned u = __float_as_uint(f);
    return (unsigned short)((u + 0x7fffu + ((u >> 16) & 1u)) >> 16);
}
__device__ __forceinline__ void ld8(const float* p, float* f) {
    float4 a = *(const float4*)p, b = *(const float4*)(p + 4);
    f[0]=a.x; f[1]=a.y; f[2]=a.z; f[3]=a.w; f[4]=b.x; f[5]=b.y; f[6]=b.z; f[7]=b.w;
}
__device__ __forceinline__ uint4 pack8(const float* f, float scale) {
    union { uint4 v; unsigned short s[8]; } w;
    #pragma unroll
    for (int j = 0; j < 8; j++) w.s[j] = f2bf(f[j] * scale);
    return w.v;
}
// combine high-16s of two floats into one dword: [lo16=a.hi16, hi16=b.hi16]
__device__ __forceinline__ unsigned packhi(float a, float b) {
#if __has_builtin(__builtin_amdgcn_perm)
    return __builtin_amdgcn_perm(__float_as_uint(b), __float_as_uint(a), 0x07060302u);
#else
    return (__float_as_uint(a) >> 16) | (__float_as_uint(b) & 0xffff0000u);
#endif
}
__device__ __forceinline__ bf16x8 mk_bf16x8(unsigned d0, unsigned d1,
                                            unsigned d2, unsigned d3) {
    union { unsigned u[4]; bf16x8 v; } w;
    w.u[0] = d0; w.u[1] = d1; w.u[2] = d2; w.u[3] = d3;
    return w.v;
}

// ---- pre-pass: per block (st, bh): V 64x64 tile -> bf16 V^T tile, plus a
// 4096-elem chunk of Q (scaled) and K -> bf16.
__global__ __launch_bounds__(256) void prep(
    const float* __restrict__ Qf, const float* __restrict__ Kf,
    const float* __restrict__ Vf, unsigned short* __restrict__ qb,
    unsigned short* __restrict__ kb, unsigned short* __restrict__ vtb)
{
    const int st = blockIdx.x, bh = blockIdx.y;
    __shared__ unsigned lt32[64][LDP / 2];   // dword view: 36 dwords/row
    const float* vp = Vf + ((size_t)bh * S_LEN + st * 64) * DHDIM;
    {
        const int c = threadIdx.x;
        const int sp = c >> 3;            // s-pair index 0..31
        const int d0 = (c & 7) * 8;
        float fa[8], fb[8];
        ld8(vp + (2 * sp) * DHDIM + d0, fa);
        ld8(vp + (2 * sp + 1) * DHDIM + d0, fb);
        #pragma unroll
        for (int j = 0; j < 8; j++) {
            int d = d0 + j;
            int colw = (sp & 3) | ((((sp >> 2) ^ (d >> 3)) & 7) << 2);
            lt32[d][colw] = (unsigned)f2bf(fa[j]) | ((unsigned)f2bf(fb[j]) << 16);
        }
    }
    size_t off = ((size_t)(bh * 32 + st) * 4096) + (size_t)threadIdx.x * 16;
    float f[8];
    ld8(Qf + off, f);     *(uint4*)(qb + off)     = pack8(f, QSCALE);
    ld8(Qf + off + 8, f); *(uint4*)(qb + off + 8) = pack8(f, QSCALE);
    ld8(Kf + off, f);     *(uint4*)(kb + off)     = pack8(f, 1.0f);
    ld8(Kf + off + 8, f); *(uint4*)(kb + off + 8) = pack8(f, 1.0f);
    __syncthreads();
    unsigned short* op = vtb + (size_t)bh * DHDIM * S_LEN + st * 64;
    for (int c = threadIdx.x; c < 512; c += 256) {
        int d = c >> 3, q = c & 7;
        int colw = ((q ^ (d >> 3)) & 7) << 2;
        *(uint4*)(op + (size_t)d * S_LEN + q * 8) = *(const uint4*)&lt32[d][colw];
    }
}

// ---- main: block = (bh, rank). 512 thr, 8 waves = (kh, qh 0..3). 128 q-rows.
__global__ __launch_bounds__(512) void fattn_splitk(
    const unsigned short* __restrict__ Qp, const unsigned short* __restrict__ Kp,
    const unsigned short* __restrict__ Vp,
    float* __restrict__ pO, float* __restrict__ pL, float* __restrict__ O)
{
    __shared__ unsigned short smem[256 * LDP]; // ksA | ksB | vtsA | vtsB (36.9KB)
    unsigned short (*ksA)[LDP]  = (unsigned short(*)[LDP])smem;
    unsigned short (*ksB)[LDP]  = (unsigned short(*)[LDP])(smem + 64 * LDP);
    unsigned short (*vtsA)[LDP] = (unsigned short(*)[LDP])(smem + 128 * LDP);
    unsigned short (*vtsB)[LDP] = (unsigned short(*)[LDP])(smem + 192 * LDP);

    const int bh   = blockIdx.x;             // 0..31
    const unsigned e = RTAB32[blockIdx.y];   // 0..31, longest-first
    const int qp   = e >> 24;
    const int k0   = (e >> 16) & 255;
    const int k1   = (e >> 8) & 255;
    const int sl   = e & 255;
    const bool whole = (sl == 255);

    const int tid  = threadIdx.x;
    const int wave = tid >> 6, lane = tid & 63;
    const int q31  = lane & 31, hi = lane >> 5;
    const int qh   = wave & 3, kh = wave >> 2;
    const int qrow = qh * 32 + q31;              // local q row 0..127
    const int gq   = qp * 128 + qrow;            // global q row
    const int diag_kt = gq >> 6;                 // wave-uniform (32-row groups)

    // ---- Q B-fragments, direct from global (pre-scaled bf16 from prep)
    const unsigned short* qsrc = Qp + ((size_t)bh * S_LEN + gq) * DHDIM;
    const bf16x8 bq0 = *(const bf16x8*)(qsrc + hi * 8);
    const bf16x8 bq1 = *(const bf16x8*)(qsrc + 16 + hi * 8);
    const bf16x8 bq2 = *(const bf16x8*)(qsrc + 32 + hi * 8);
    const bf16x8 bq3 = *(const bf16x8*)(qsrc + 48 + hi * 8);

    f32x16 of2[2];   // PV partials over own kh k-slice, both d-halves
    #pragma unroll
    for (int i = 0; i < 16; i++) { of2[0][i] = 0.f; of2[1][i] = 0.f; }
    float l_p = 0.f;

    // ---- staging + prefetch: 512 threads, 1 uint4/thread per matrix
    const unsigned short* Kbh = Kp + (size_t)bh * S_LEN * DHDIM;
    const unsigned short* Vbh = Vp + (size_t)bh * DHDIM * S_LEN;
    const int sr = tid >> 3, sc = (tid & 7) * 8;   // rows 0..63
    uint4 kr, vr;
    kr = *(const uint4*)(Kbh + ((size_t)k0 * 64 + sr) * DHDIM + sc);
    vr = *(const uint4*)(Vbh + (size_t)sr * S_LEN + k0 * 64 + sc);
    {   // prologue: write tile k0 into its buffer
        unsigned short (*ks)[LDP]  = (k0 & 1) ? ksB : ksA;
        unsigned short (*vts)[LDP] = (k0 & 1) ? vtsB : vtsA;
        *(uint4*)&ks[sr][sc]  = kr;
        *(uint4*)&vts[sr][sc] = vr;
    }
    if (k0 + 1 < k1) {
        kr = *(const uint4*)(Kbh + ((size_t)(k0 + 1) * 64 + sr) * DHDIM + sc);
        vr = *(const uint4*)(Vbh + (size_t)sr * S_LEN + (k0 + 1) * 64 + sc);
    }

    for (int kt = k0; kt < k1; kt++) {
        __syncthreads();  // buf[kt&1] written; prior reads of buf[(kt+1)&1] done

        if (kt + 1 < k1) {  // write next tile's buffer; prefetch kt+2
            unsigned short (*ks)[LDP]  = ((kt + 1) & 1) ? ksB : ksA;
            unsigned short (*vts)[LDP] = ((kt + 1) & 1) ? vtsB : vtsA;
            *(uint4*)&ks[sr][sc]  = kr;
            *(uint4*)&vts[sr][sc] = vr;
            if (kt + 2 < k1) {
                kr = *(const uint4*)(Kbh + ((size_t)(kt + 2) * 64 + sr) * DHDIM + sc);
                vr = *(const uint4*)(Vbh + (size_t)sr * S_LEN + (kt + 2) * 64 + sc);
            }
        }

        if (kt > diag_kt) continue;  // fully-masked tile for this wave: skip

        const unsigned short (*ksc)[LDP] = (kt & 1) ? ksB : ksA;
        const unsigned short (*vtc)[LDP] = (kt & 1) ? vtsB : vtsA;

        // ---- St(kt): quadrant (kh, qh); A = K read once, B = Q in regs
        f32x16 sf;
        #pragma unroll
        for (int i = 0; i < 16; i++) sf[i] = -M2;
        __builtin_amdgcn_s_setprio(1);
        {
            bf16x8 ak = *(const bf16x8*)&ksc[kh * 32 + q31][hi * 8];
            sf = __builtin_amdgcn_mfma_f32_32x32x16_bf16(ak, bq0, sf, 0, 0, 0);
            ak = *(const bf16x8*)&ksc[kh * 32 + q31][16 + hi * 8];
            sf = __builtin_amdgcn_mfma_f32_32x32x16_bf16(ak, bq1, sf, 0, 0, 0);
            ak = *(const bf16x8*)&ksc[kh * 32 + q31][32 + hi * 8];
            sf = __builtin_amdgcn_mfma_f32_32x32x16_bf16(ak, bq2, sf, 0, 0, 0);
            ak = *(const bf16x8*)&ksc[kh * 32 + q31][48 + hi * 8];
            sf = __builtin_amdgcn_mfma_f32_32x32x16_bf16(ak, bq3, sf, 0, 0, 0);
        }
        __builtin_amdgcn_s_setprio(0);

        // ---- softmax numerator -> packed pdw; l accumulates in VALU
        const bool diag = (kt == diag_kt);
        const int qmod = gq & 63;
        unsigned pdw[8];
        #pragma unroll
        for (int g = 0; g < 4; g++) {
            float p[4];
            #pragma unroll
            for (int r2 = 0; r2 < 4; r2++) {
                float pv = fast_exp2(sf[g * 4 + r2]);
                if (diag) {
                    const int kl = kh * 32 + 8 * g + 4 * hi + r2;
                    if (kl > qmod) pv = 0.f;
                }
                p[r2] = pv;
                l_p += pv;
            }
            pdw[g * 2]     = packhi(p[0], p[1]);
            pdw[g * 2 + 1] = packhi(p[2], p[3]);
        }

        // ---- PV(kt) in-register: hi-half swap turns D-layout into B-frag
        __builtin_amdgcn_s_setprio(1);
        #pragma unroll
        for (int js = 0; js < 2; js++) {
            const unsigned a0 = pdw[4 * js],     a1 = pdw[4 * js + 1];
            const unsigned b0 = pdw[4 * js + 2], b1 = pdw[4 * js + 3];
            const unsigned pa0 = __shfl_xor(a0, 32), pa1 = __shfl_xor(a1, 32);
            const unsigned pb0 = __shfl_xor(b0, 32), pb1 = __shfl_xor(b1, 32);
            const bf16x8 bp = mk_bf16x8(hi ? pb0 : a0, hi ? pb1 : a1,
                                        hi ? b0 : pa0, hi ? b1 : pa1);
            const int scol = (2 * kh + js) * 16 + hi * 8;
            bf16x8 av = *(const bf16x8*)&vtc[q31][scol];
            of2[0] = __builtin_amdgcn_mfma_f32_32x32x16_bf16(av, bp, of2[0], 0, 0, 0);
            av = *(const bf16x8*)&vtc[32 + q31][scol];
            of2[1] = __builtin_amdgcn_mfma_f32_32x32x16_bf16(av, bp, of2[1], 0, 0, 0);
        }
        __builtin_amdgcn_s_setprio(0);
    }

    // ---- epilogue: l across hi, then cross-kh reduction of O + l via LDS
    float l2 = l_p + __shfl_xor(l_p, 32);
    __syncthreads();                  // all tiles done; smem reusable
    float* fs = (float*)smem;
    const int base = (qh * 64 + lane) * 36;   // 4x64x36 floats = 36864B exact
    if (kh == 1) {
        #pragma unroll
        for (int dh = 0; dh < 2; dh++)
            #pragma unroll
            for (int g = 0; g < 4; g++)
                *(float4*)&fs[base + dh * 16 + g * 4] = make_float4(
                    of2[dh][4 * g], of2[dh][4 * g + 1],
                    of2[dh][4 * g + 2], of2[dh][4 * g + 3]);
        fs[base + 32] = l2;
    }
    __syncthreads();
    if (kh == 0) {
        #pragma unroll
        for (int dh = 0; dh < 2; dh++)
            #pragma unroll
            for (int g = 0; g < 4; g++) {
                float4 a = *(const float4*)&fs[base + dh * 16 + g * 4];
                of2[dh][4 * g]     += a.x;
                of2[dh][4 * g + 1] += a.y;
                of2[dh][4 * g + 2] += a.z;
                of2[dh][4 * g + 3] += a.w;
            }
        l2 += fs[base + 32];

        // lane holds O[d = dh*32 + 8g + 4hi + r][q = gq], full K-range
        if (whole) {
            const float inv = 1.f / l2;
            float* op = O + ((size_t)bh * S_LEN + gq) * DHDIM;
            #pragma unroll
            for (int dh = 0; dh < 2; dh++)
                #pragma unroll
                for (int g = 0; g < 4; g++)
                    *(float4*)(op + dh * 32 + 8 * g + 4 * hi) = make_float4(
                        of2[dh][4 * g] * inv, of2[dh][4 * g + 1] * inv,
                        of2[dh][4 * g + 2] * inv, of2[dh][4 * g + 3] * inv);
        } else {
            const int slot = bh * NSLOT + sl;
            if (hi == 0) pL[slot * 128 + qrow] = l2;
            float* op = pO + (size_t)slot * 8192 + qrow * 64;
            #pragma unroll
            for (int dh = 0; dh < 2; dh++)
                #pragma unroll
                for (int g = 0; g < 4; g++)
                    *(float4*)(op + dh * 32 + 8 * g + 4 * hi) = make_float4(
                        of2[dh][4 * g], of2[dh][4 * g + 1],
                        of2[dh][4 * g + 2], of2[dh][4 * g + 3]);
        }
    }
}

// ---- combine: O = sum(Oi) / sum(li), per (bh, qp) for qp in [5,15]
__global__ __launch_bounds__(256) void combine(
    const float* __restrict__ pO, const float* __restrict__ pL,
    float* __restrict__ O)
{
    const int t = 5 + blockIdx.x, bh = blockIdx.y;
    int base, cnt;
    if (t <= 10) { base = (t - 5) * 2;       cnt = 2; }
    else         { base = 12 + (t - 11) * 3; cnt = 3; }
    const int sb = bh * NSLOT + base;
    const float* A = pO + (size_t)sb * 8192;
    float* out = O + ((size_t)bh * S_LEN + t * 128) * DHDIM;
    #pragma unroll
    for (int k = 0; k < 8; k++) {
        int c = threadIdx.x + k * 256;     // float4 chunk 0..2047
        int row = c >> 4;                  // 0..127
        float l = pL[sb * 128 + row] + pL[(sb + 1) * 128 + row];
        float4 a = *(const float4*)(A + c * 4);
        float4 b = *(const float4*)(A + 8192 + c * 4);
        float4 s = make_float4(a.x + b.x, a.y + b.y, a.z + b.z, a.w + b.w);
        if (cnt == 3) {
            l += pL[(sb + 2) * 128 + row];
            float4 d = *(const float4*)(A + 16384 + c * 4);
            s = make_float4(s.x + d.x, s.y + d.y, s.z + d.z, s.w + d.w);
        }
        float inv = 1.f / l;
        *(float4*)(out + c * 4) = make_float4(
            s.x * inv, s.y * inv, s.z * inv, s.w * inv);
    }
}

// ---- fallback kernels (whole-row blocks), used when ws too small
template <bool PRE>
__global__ __launch_bounds__(256) void fattn_kernel(
    const void* __restrict__ Qp, const void* __restrict__ Kp,
    const void* __restrict__ Vp, float* __restrict__ O)
{
    __shared__ unsigned short smem[192 * LDP];
    unsigned short (*ks)[LDP]  = (unsigned short(*)[LDP])smem;
    unsigned short (*vts)[LDP] = (unsigned short(*)[LDP])(smem + 64 * LDP);
    unsigned short (*qs)[LDP]  = (unsigned short(*)[LDP])(smem + 128 * LDP);
    unsigned short (*pst)[LDP] = qs;

    const int id = blockIdx.y * 32 + blockIdx.x;
    const int g  = id >> 8;
    const int r8 = id & 255;
    const int bh = r8 >> 3;
    const int s8 = r8 & 7;
    const int qt = (g == 0) ? 31 - 2 * s8 : (g == 1) ? 2 * s8
                 : (g == 2) ? 30 - 2 * s8 : 2 * s8 + 1;

    const int tid = threadIdx.x;
    const int wave = tid >> 6, lane = tid & 63;
    const int quad = lane >> 4, l16 = lane & 15;

    if constexpr (PRE) {
        const unsigned short* src = (const unsigned short*)Qp
            + ((size_t)bh * S_LEN + qt * 64) * DHDIM;
        for (int c = tid; c < 512; c += 256) {
            int row = c >> 3, c8 = (c & 7) * 8;
            *(uint4*)&qs[row][c8] = *(const uint4*)(src + row * DHDIM + c8);
        }
    } else {
        const float* src = (const float*)Qp + ((size_t)bh * S_LEN + qt * 64) * DHDIM;
        for (int c = tid; c < 512; c += 256) {
            int row = c >> 3, c8 = (c & 7) * 8;
            float f[8]; ld8(src + row * DHDIM + c8, f);
            *(uint4*)&qs[row][c8] = pack8(f, QSCALE);
        }
    }
    __syncthreads();

    const int prow = wave * 16 + l16;
    const bf16x8 bq0 = *(const bf16x8*)&qs[prow][quad * 8];
    const bf16x8 bq1 = *(const bf16x8*)&qs[prow][32 + quad * 8];

    float l_p = 0.f;
    f32x4 of[4];
    #pragma unroll
    for (int n = 0; n < 4; n++) of[n] = (f32x4){0.f, 0.f, 0.f, 0.f};

    for (int kt = 0; kt <= qt; kt++) {
        __syncthreads();
        if constexpr (PRE) {
            const unsigned short* ksrc = (const unsigned short*)Kp
                + ((size_t)bh * S_LEN + kt * 64) * DHDIM;
            const unsigned short* vsrc = (const unsigned short*)Vp
                + (size_t)bh * DHDIM * S_LEN + kt * 64;
            for (int c = tid; c < 512; c += 256) {
                int row = c >> 3, c8 = (c & 7) * 8;
                *(uint4*)&ks[row][c8]  = *(const uint4*)(ksrc + row * DHDIM + c8);
                *(uint4*)&vts[row][c8] = *(const uint4*)(vsrc + (size_t)row * S_LEN + c8);
            }
        } else {
            const float* ksrc = (const float*)Kp + ((size_t)bh * S_LEN + kt * 64) * DHDIM;
            const float* vsrc = (const float*)Vp + ((size_t)bh * S_LEN + kt * 64) * DHDIM;
            for (int c = tid; c < 512; c += 256) {
                int row = c >> 3, c8 = (c & 7) * 8;
                float f[8];
                ld8(ksrc + row * DHDIM + c8, f);
                *(uint4*)&ks[row][c8] = pack8(f, 1.0f);
                ld8(vsrc + row * DHDIM + c8, f);
                #pragma unroll
                for (int j = 0; j < 8; j++) vts[c8 + j][row] = f2bf(f[j]);
            }
        }
        __syncthreads();

        f32x4 sf[4];
        #pragma unroll
        for (int n = 0; n < 4; n++) {
            bf16x8 ak0 = *(const bf16x8*)&ks[n * 16 + l16][quad * 8];
            bf16x8 ak1 = *(const bf16x8*)&ks[n * 16 + l16][32 + quad * 8];
            sf[n] = (f32x4){-M2, -M2, -M2, -M2};
            sf[n] = __builtin_amdgcn_mfma_f32_16x16x32_bf16(ak0, bq0, sf[n], 0, 0, 0);
            sf[n] = __builtin_amdgcn_mfma_f32_16x16x32_bf16(ak1, bq1, sf[n], 0, 0, 0);
        }

        const bool diag = (kt == qt);
        #pragma unroll
        for (int n = 0; n < 4; n++) {
            float p[4];
            #pragma unroll
            for (int r = 0; r < 4; r++) {
                p[r] = fast_exp2(sf[n][r]);
                if (diag && (n * 16 + quad * 4 + r > prow)) p[r] = 0.f;
                l_p += p[r];
            }
            uint2 dw;
            dw.x = packhi(p[0], p[1]);
            dw.y = packhi(p[2], p[3]);
            *(uint2*)&pst[prow][n * 16 + quad * 4] = dw;
        }
        asm volatile("s_waitcnt lgkmcnt(0)" ::: "memory");

        bf16x8 bp0 = *(const bf16x8*)&pst[prow][quad * 8];
        bf16x8 bp1 = *(const bf16x8*)&pst[prow][32 + quad * 8];
        #pragma unroll
        for (int n = 0; n < 4; n++) {
            bf16x8 av0 = *(const bf16x8*)&vts[n * 16 + l16][quad * 8];
            bf16x8 av1 = *(const bf16x8*)&vts[n * 16 + l16][32 + quad * 8];
            of[n] = __builtin_amdgcn_mfma_f32_16x16x32_bf16(av0, bp0, of[n], 0, 0, 0);
            of[n] = __builtin_amdgcn_mfma_f32_16x16x32_bf16(av1, bp1, of[n], 0, 0, 0);
        }
    }

    l_p += __shfl_xor(l_p, 16);
    l_p += __shfl_xor(l_p, 32);
    const float inv = 1.f / l_p;
    float* op = O + ((size_t)bh * S_LEN + qt * 64 + prow) * DHDIM;
    #pragma unroll
    for (int n = 0; n < 4; n++)
        *(float4*)(op + n * 16 + quad * 4) = make_float4(
            of[n][0] * inv, of[n][1] * inv, of[n][2] * inv, of[n][3] * inv);
}

extern "C" void kernel_launch(void* const* d_in, const int* in_sizes, int n_in,
                              void* d_out, int out_size, void* d_ws, size_t ws_size,
                              hipStream_t stream) {
    const float* Q = (const float*)d_in[0];
    const float* K = (const float*)d_in[1];
    const float* V = (const float*)d_in[2];
    // d_in[3] = causal mask: analytic, not read.
    float* O = (float*)d_out;
    const size_t N = (size_t)NHEADS * S_LEN * DHDIM;      // 4,194,304 elems
    const size_t prepB  = 3 * N * sizeof(unsigned short); // 25.2 MB
    // 27 partial slots per bh (128-row q-pair pieces): O-partials + l
    const size_t partB  = (size_t)NSLOT * 32 * (8192 + 128) * sizeof(float); // 28.8 MB

    if (d_ws && ws_size >= prepB + partB) {
        unsigned short* qb  = (unsigned short*)d_ws;
        unsigned short* kb  = qb + N;
        unsigned short* vtb = kb + N;
        float* pO = (float*)((char*)d_ws + prepB);
        float* pL = pO + (size_t)NSLOT * 32 * 8192;
        prep<<<dim3(S_LEN / 64, NHEADS), 256, 0, stream>>>(Q, K, V, qb, kb, vtb);
        fattn_splitk<<<dim3(32, 32), 512, 0, stream>>>(qb, kb, vtb, pO, pL, O);
        combine<<<dim3(11, 32), 256, 0, stream>>>(pO, pL, O);
    } else if (d_ws && ws_size >= prepB) {
        unsigned short* qb  = (unsigned short*)d_ws;
        unsigned short* kb  = qb + N;
        unsigned short* vtb = kb + N;
        prep<<<dim3(S_LEN / 64, NHEADS), 256, 0, stream>>>(Q, K, V, qb, kb, vtb);
        fattn_kernel<true><<<dim3(32, 32), 256, 0, stream>>>(qb, kb, vtb, O);
    } else {
        fattn_kernel<false><<<dim3(32, 32), 256, 0, stream>>>(Q, K, V, O);
    }
}